// Round 4
// baseline (1524.923 us; speedup 1.0000x reference)
//
#include <hip/hip_runtime.h>

#define N_NODES 100000
#define F_IN 128
#define HID 64
#define OUT_F 300
#define KCAT 256            // F_IN * 2 (mean | x)
#define WO_ROWS 320         // 300 padded to 20 tiles of 16
#define NBKT 782            // ceil(100000 / 128) buckets of 128 nodes
#define BCAP 16             // staging slots per bucket (flush = 64B line)

typedef short bf8 __attribute__((ext_vector_type(8)));
typedef float f32x4 __attribute__((ext_vector_type(4)));
typedef unsigned short us4 __attribute__((ext_vector_type(4)));

__device__ inline unsigned short f2bf(float f) {
    unsigned u = __builtin_bit_cast(unsigned, f);
    u += 0x7fff + ((u >> 16) & 1);          // round-to-nearest-even
    return (unsigned short)(u >> 16);
}
__device__ inline float b2f(unsigned short h) {
    return __builtin_bit_cast(float, (unsigned)h << 16);
}

// ------------------------------------------------------------------ zero bucket hist
__global__ void k_zerob(int* __restrict__ gbh) {
    int i = blockIdx.x * blockDim.x + threadIdx.x;
    if (i < NBKT) gbh[i] = 0;
}

// ------------------------------------------------------------------ bucket histogram (LDS-local)
__global__ __launch_bounds__(256) void k_bhist(const int* __restrict__ ei,
                                               int* __restrict__ gbh, int nE) {
    __shared__ int h[NBKT];
    const int tid = threadIdx.x;
    for (int i = tid; i < NBKT; i += 256) h[i] = 0;
    __syncthreads();
    const int per = (nE + gridDim.x - 1) / gridDim.x;
    const int e0 = blockIdx.x * per;
    const int e1 = min(e0 + per, nE);
    for (int e = e0 + tid; e < e1; e += 256)
        atomicAdd(&h[ei[nE + e] >> 7], 1);
    __syncthreads();
    for (int i = tid; i < NBKT; i += 256)
        if (h[i]) atomicAdd(&gbh[i], h[i]);
}

// ------------------------------------------------------------------ bucket scan (16-padded bases)
__global__ __launch_bounds__(1024) void k_bscan(const int* __restrict__ gbh,
                                                int* __restrict__ bbase,
                                                int* __restrict__ gcur) {
    __shared__ int ws[16];
    const int tid = threadIdx.x, lane = tid & 63, wid = tid >> 6;
    int v = 0;
    if (tid < NBKT) v = (gbh[tid] + 15) & ~15;      // pad to 16 -> 64B-aligned bases
    int s = v;
#pragma unroll
    for (int d = 1; d < 64; d <<= 1) { int t = __shfl_up(s, d, 64); if (lane >= d) s += t; }
    if (lane == 63) ws[wid] = s;
    __syncthreads();
    if (tid < 16) {
        int wv = ws[tid];
        int ps = wv;
#pragma unroll
        for (int d = 1; d < 16; d <<= 1) { int t = __shfl_up(ps, d, 16); if (tid >= d) ps += t; }
        ws[tid] = ps;                                // inclusive
    }
    __syncthreads();
    int excl = ((wid == 0) ? 0 : ws[wid - 1]) + (s - v);
    if (tid < NBKT) { bbase[tid] = excl; gcur[tid] = excl; }
}

// ------------------------------------------------------------------ LDS-staged partition
// Packs src<<7 | (dst&127) into u32; flushes 16-entry (64B) groups so L2 lines
// are fully written back-to-back -> no scattered-write amplification.
__global__ __launch_bounds__(256, 2) void k_part(const int* __restrict__ ei,
                                                 int* __restrict__ gcur,
                                                 unsigned* __restrict__ pedges, int nE) {
    __shared__ unsigned buf[NBKT][BCAP];     // 50 KB
    __shared__ int bcnt[NBKT];
    __shared__ unsigned rpk[256];
    __shared__ int rbk[256];
    __shared__ int rcnt;
    const int tid = threadIdx.x;
    for (int i = tid; i < NBKT; i += 256) bcnt[i] = 0;
    if (tid == 0) rcnt = 0;
    __syncthreads();
    const int per = (nE + gridDim.x - 1) / gridDim.x;
    const int e0 = blockIdx.x * per;
    const int e1 = min(e0 + per, nE);
    for (int base = e0; base < e1; base += 256) {
        const int e = base + tid;
        if (e < e1) {
            int src = ei[e];
            int dst = ei[nE + e];
            int b = dst >> 7;
            unsigned pk = ((unsigned)src << 7) | (unsigned)(dst & 127);
            int pos = atomicAdd(&bcnt[b], 1);
            if (pos < BCAP) buf[b][pos] = pk;
            else { int r = atomicAdd(&rcnt, 1); rpk[r] = pk; rbk[r] = b; }
        }
        __syncthreads();
        while (true) {
            // flush full buckets (each bucket owned by exactly one thread)
            for (int bb = tid; bb < NBKT; bb += 256) {
                if (bcnt[bb] >= BCAP) {
                    int gp = atomicAdd(&gcur[bb], BCAP);
#pragma unroll
                    for (int i = 0; i < BCAP; ++i) pedges[gp + i] = buf[bb][i];
                    bcnt[bb] = 0;        // overflow entries live in rpk/rbk
                }
            }
            __syncthreads();
            int nr = rcnt;
            unsigned mpk = 0; int mb = -1;
            if (tid < nr) { mpk = rpk[tid]; mb = rbk[tid]; }
            __syncthreads();
            if (nr == 0) break;
            if (tid == 0) rcnt = 0;
            __syncthreads();
            if (mb >= 0) {
                int pos = atomicAdd(&bcnt[mb], 1);
                if (pos < BCAP) buf[mb][pos] = mpk;
                else { int r = atomicAdd(&rcnt, 1); rpk[r] = mpk; rbk[r] = mb; }
            }
            __syncthreads();
        }
    }
    // final drain (partial, dword stores)
    for (int bb = tid; bb < NBKT; bb += 256) {
        int c = bcnt[bb];
        if (c > 0) {
            int gp = atomicAdd(&gcur[bb], c);
            for (int i = 0; i < c; ++i) pedges[gp + i] = buf[bb][i];
        }
    }
}

// ------------------------------------------------------------------ x -> bf16 into A[:,128:256]
__global__ void k_cvt(const float* __restrict__ x, unsigned short* __restrict__ A) {
    int idx = blockIdx.x * blockDim.x + threadIdx.x;    // float4 index
    const int total = N_NODES * F_IN / 4;
    if (idx >= total) return;
    int n = idx >> 5;
    int c4 = idx & 31;
    float4 v = ((const float4*)x)[idx];
    us4 r; r[0] = f2bf(v.x); r[1] = f2bf(v.y); r[2] = f2bf(v.z); r[3] = f2bf(v.w);
    *reinterpret_cast<us4*>(A + (size_t)n * KCAT + F_IN + c4 * 4) = r;
}

// ------------------------------------------------------------------ weights -> bf16
__global__ void k_wcvt(const float* __restrict__ Wl, const float* __restrict__ Wr,
                       const float* __restrict__ Wout,
                       unsigned short* __restrict__ Wc, unsigned short* __restrict__ Wo) {
    int idx = blockIdx.x * blockDim.x + threadIdx.x;
    if (idx < HID * KCAT) {
        int f = idx >> 8, k = idx & 255;
        float v = (k < F_IN) ? Wl[f * F_IN + k] : Wr[f * F_IN + (k - F_IN)];
        Wc[idx] = f2bf(v);
    } else {
        int j = idx - HID * KCAT;
        if (j < WO_ROWS * HID) {
            int o = j >> 6, k = j & 63;
            Wo[j] = (o < OUT_F) ? f2bf(Wout[o * HID + k]) : (unsigned short)0;
        }
    }
}

// ------------------------------------------------------------------ bucket aggregation (mean)
// One block per 128-node bucket; fp32 accumulator in LDS (conflict-free: lane l
// owns feats l and l+64 -> banks (4*local+l)&31, 2-way = free). Gathers batched
// 4 edges deep to overlap L3 latency.
__global__ __launch_bounds__(256, 2) void k_agg2(unsigned short* __restrict__ A,
                                                 const unsigned* __restrict__ pedges,
                                                 const int* __restrict__ bbase,
                                                 const int* __restrict__ gbh) {
    __shared__ float acc[128][132];          // 67.6 KB
    __shared__ int deg[128];
    const int tid = threadIdx.x, lane = tid & 63, wv = tid >> 6;
    const int bkt = blockIdx.x;
    for (int i = tid; i < 128 * 132; i += 256) ((float*)acc)[i] = 0.f;
    if (tid < 128) deg[tid] = 0;
    __syncthreads();
    const int base = bbase[bkt];
    const int cnt = gbh[bkt];
    for (int c0 = wv * 64; c0 < cnt; c0 += 256) {
        int myi = c0 + lane;
        unsigned mypk = (myi < cnt) ? pedges[base + myi] : 0u;
        int m = min(64, cnt - c0);
        int j = 0;
        for (; j + 4 <= m; j += 4) {
            unsigned p0 = __shfl((int)mypk, j + 0, 64);
            unsigned p1 = __shfl((int)mypk, j + 1, 64);
            unsigned p2 = __shfl((int)mypk, j + 2, 64);
            unsigned p3 = __shfl((int)mypk, j + 3, 64);
            const unsigned short* r0 = A + (size_t)(p0 >> 7) * KCAT + F_IN;
            const unsigned short* r1 = A + (size_t)(p1 >> 7) * KCAT + F_IN;
            const unsigned short* r2 = A + (size_t)(p2 >> 7) * KCAT + F_IN;
            const unsigned short* r3 = A + (size_t)(p3 >> 7) * KCAT + F_IN;
            unsigned short a0 = r0[lane], b0 = r0[lane + 64];
            unsigned short a1 = r1[lane], b1 = r1[lane + 64];
            unsigned short a2 = r2[lane], b2 = r2[lane + 64];
            unsigned short a3 = r3[lane], b3 = r3[lane + 64];
            atomicAdd(&acc[p0 & 127][lane], b2f(a0));
            atomicAdd(&acc[p0 & 127][lane + 64], b2f(b0));
            atomicAdd(&acc[p1 & 127][lane], b2f(a1));
            atomicAdd(&acc[p1 & 127][lane + 64], b2f(b1));
            atomicAdd(&acc[p2 & 127][lane], b2f(a2));
            atomicAdd(&acc[p2 & 127][lane + 64], b2f(b2));
            atomicAdd(&acc[p3 & 127][lane], b2f(a3));
            atomicAdd(&acc[p3 & 127][lane + 64], b2f(b3));
            if (lane == 0) {
                atomicAdd(&deg[p0 & 127], 1);
                atomicAdd(&deg[p1 & 127], 1);
                atomicAdd(&deg[p2 & 127], 1);
                atomicAdd(&deg[p3 & 127], 1);
            }
        }
        for (; j < m; ++j) {
            unsigned p0 = __shfl((int)mypk, j, 64);
            const unsigned short* r0 = A + (size_t)(p0 >> 7) * KCAT + F_IN;
            unsigned short a0 = r0[lane], b0 = r0[lane + 64];
            atomicAdd(&acc[p0 & 127][lane], b2f(a0));
            atomicAdd(&acc[p0 & 127][lane + 64], b2f(b0));
            if (lane == 0) atomicAdd(&deg[p0 & 127], 1);
        }
    }
    __syncthreads();
    // mean + bf16 write into A[node][0:128]
    int local = tid >> 1;
    int half = (tid & 1) * 64;
    int node = bkt * 128 + local;
    if (node < N_NODES) {
        float inv = 1.0f / fmaxf((float)deg[local], 1.0f);
        unsigned short* dst = A + (size_t)node * KCAT + half;
        for (int q = 0; q < 64; q += 4) {
            us4 r;
            r[0] = f2bf(acc[local][half + q + 0] * inv);
            r[1] = f2bf(acc[local][half + q + 1] * inv);
            r[2] = f2bf(acc[local][half + q + 2] * inv);
            r[3] = f2bf(acc[local][half + q + 3] * inv);
            *reinterpret_cast<us4*>(dst + q) = r;
        }
    }
}

// ------------------------------------------------------------------ fused MFMA: h-GEMM + out-GEMM
__global__ __launch_bounds__(64) void k_fused(
    const unsigned short* __restrict__ A, const unsigned short* __restrict__ Wc,
    const float* __restrict__ bl, const unsigned short* __restrict__ Wo,
    const float* __restrict__ bout, float* __restrict__ out) {

    __shared__ __align__(16) unsigned short hs[64 * 64];
    const int nb = blockIdx.x * 64;
    const int lane = threadIdx.x;
    const int lm = lane & 15, lk = lane >> 4;

    f32x4 acc[4][4];
#pragma unroll
    for (int a = 0; a < 4; ++a)
#pragma unroll
        for (int b = 0; b < 4; ++b) acc[a][b] = f32x4{0.f, 0.f, 0.f, 0.f};

#pragma unroll
    for (int kt = 0; kt < 8; ++kt) {
        const int ko = kt * 32 + lk * 8;
        bf8 af[4], bw[4];
#pragma unroll
        for (int mt = 0; mt < 4; ++mt) {
            int row = nb + mt * 16 + lm;
            if (row >= N_NODES) row = N_NODES - 1;
            af[mt] = *reinterpret_cast<const bf8*>(A + (size_t)row * KCAT + ko);
        }
#pragma unroll
        for (int nt = 0; nt < 4; ++nt)
            bw[nt] = *reinterpret_cast<const bf8*>(Wc + (nt * 16 + lm) * KCAT + ko);
#pragma unroll
        for (int mt = 0; mt < 4; ++mt)
#pragma unroll
            for (int nt = 0; nt < 4; ++nt)
                acc[mt][nt] = __builtin_amdgcn_mfma_f32_16x16x32_bf16(af[mt], bw[nt], acc[mt][nt], 0, 0, 0);
    }

#pragma unroll
    for (int nt = 0; nt < 4; ++nt) {
        float bv = bl[nt * 16 + lm];
#pragma unroll
        for (int mt = 0; mt < 4; ++mt)
#pragma unroll
            for (int r = 0; r < 4; ++r) {
                int rowl = mt * 16 + lk * 4 + r;
                int cb = (nt * 32 + lm * 2) ^ ((rowl & 7) << 4);
                float v = fmaxf(acc[mt][nt][r] + bv, 0.f);
                hs[rowl * 64 + (cb >> 1)] = f2bf(v);
            }
    }
    __syncthreads();

    bf8 ah[4][2];
#pragma unroll
    for (int mt = 0; mt < 4; ++mt)
#pragma unroll
        for (int k2 = 0; k2 < 2; ++k2) {
            int rowl = mt * 16 + lm;
            int cb = (k2 * 64 + lk * 16) ^ ((rowl & 7) << 4);
            ah[mt][k2] = *reinterpret_cast<const bf8*>(
                reinterpret_cast<const char*>(hs) + rowl * 128 + cb);
        }

    for (int g = 0; g < 5; ++g) {
        f32x4 acc2[4][4];
#pragma unroll
        for (int a = 0; a < 4; ++a)
#pragma unroll
            for (int b = 0; b < 4; ++b) acc2[a][b] = f32x4{0.f, 0.f, 0.f, 0.f};
#pragma unroll
        for (int k2 = 0; k2 < 2; ++k2) {
            bf8 bw[4];
#pragma unroll
            for (int nt = 0; nt < 4; ++nt)
                bw[nt] = *reinterpret_cast<const bf8*>(
                    Wo + (size_t)((g * 4 + nt) * 16 + lm) * HID + k2 * 32 + lk * 8);
#pragma unroll
            for (int mt = 0; mt < 4; ++mt)
#pragma unroll
                for (int nt = 0; nt < 4; ++nt)
                    acc2[mt][nt] = __builtin_amdgcn_mfma_f32_16x16x32_bf16(ah[mt][k2], bw[nt], acc2[mt][nt], 0, 0, 0);
        }
#pragma unroll
        for (int nt = 0; nt < 4; ++nt) {
            int o = (g * 4 + nt) * 16 + lm;
            float bo = (o < OUT_F) ? bout[o] : 0.f;
#pragma unroll
            for (int mt = 0; mt < 4; ++mt)
#pragma unroll
                for (int r = 0; r < 4; ++r) {
                    int node = nb + mt * 16 + lk * 4 + r;
                    if (node < N_NODES && o < OUT_F)
                        out[(size_t)node * OUT_F + o] = acc2[mt][nt][r] + bo;
                }
        }
    }
}

extern "C" void kernel_launch(void* const* d_in, const int* in_sizes, int n_in,
                              void* d_out, int out_size, void* d_ws, size_t ws_size,
                              hipStream_t stream) {
    const float* x    = (const float*)d_in[0];
    const int*   ei   = (const int*)d_in[1];
    const float* Wl   = (const float*)d_in[2];
    const float* bl   = (const float*)d_in[3];
    const float* Wr   = (const float*)d_in[4];
    const float* Wout = (const float*)d_in[5];
    const float* bout = (const float*)d_in[6];
    float* out = (float*)d_out;

    int nE = in_sizes[1] / 2;

    unsigned short* A = (unsigned short*)d_ws;                  // 51.2 MB
    unsigned* pedges  = (unsigned*)(A + (size_t)N_NODES * KCAT);// 6.48 MB (padded)
    int* gbh   = (int*)(pedges + 1620000);
    int* bbase = gbh + NBKT;
    int* gcur  = bbase + NBKT;
    unsigned short* Wc = (unsigned short*)(gcur + NBKT);        // 64*256
    unsigned short* Wo = Wc + HID * KCAT;                       // 320*64

    k_wcvt<<<(HID * KCAT + WO_ROWS * HID + 255) / 256, 256, 0, stream>>>(Wl, Wr, Wout, Wc, Wo);
    k_cvt<<<(N_NODES * F_IN / 4 + 255) / 256, 256, 0, stream>>>(x, A);
    k_zerob<<<(NBKT + 255) / 256, 256, 0, stream>>>(gbh);
    k_bhist<<<512, 256, 0, stream>>>(ei, gbh, nE);
    k_bscan<<<1, 1024, 0, stream>>>(gbh, bbase, gcur);
    k_part<<<512, 256, 0, stream>>>(ei, gcur, pedges, nE);
    k_agg2<<<NBKT, 256, 0, stream>>>(A, pedges, bbase, gbh);
    k_fused<<<(N_NODES + 63) / 64, 64, 0, stream>>>(A, Wc, bl, Wo, bout, out);
}

// Round 5
// 211.946 us; speedup vs baseline: 7.1949x; 7.1949x over previous
//
#include <hip/hip_runtime.h>

#define N_NODES 100000
#define F_IN 128
#define HID 64
#define OUT_F 300
#define WO_ROWS 320         // 300 padded to 20 tiles of 16
#define NBKT 782            // ceil(100000 / 128) buckets of 128 nodes
#define BCAP 16             // k_part staging slots per bucket (flush = 64B)
#define ECAP 2688           // per-bucket edge cap (mean 2046, sigma 45 -> +14 sigma)

typedef short bf8 __attribute__((ext_vector_type(8)));
typedef float f32x4 __attribute__((ext_vector_type(4)));

__device__ inline unsigned short f2bf(float f) {
    unsigned u = __builtin_bit_cast(unsigned, f);
    u += 0x7fff + ((u >> 16) & 1);          // round-to-nearest-even
    return (unsigned short)(u >> 16);
}
__device__ inline float b2f(unsigned short h) {
    return __builtin_bit_cast(float, (unsigned)h << 16);
}

// ------------------------------------------------------------------ weights -> bf16
// Wc[c][k]: c<64 -> Wl row c ; c>=64 -> Wr row c-64. Wo[320][64] zero-padded.
__global__ void k_wcvt(const float* __restrict__ Wl, const float* __restrict__ Wr,
                       const float* __restrict__ Wout,
                       unsigned short* __restrict__ Wc, unsigned short* __restrict__ Wo) {
    int idx = blockIdx.x * blockDim.x + threadIdx.x;
    if (idx < 128 * 128) {
        int c = idx >> 7, k = idx & 127;
        float v = (c < HID) ? Wl[c * F_IN + k] : Wr[(c - HID) * F_IN + k];
        Wc[idx] = f2bf(v);
    } else {
        int j = idx - 128 * 128;
        if (j < WO_ROWS * HID) {
            int o = j >> 6, k = j & 63;
            Wo[j] = (o < OUT_F) ? f2bf(Wout[o * HID + k]) : (unsigned short)0;
        }
    }
}

// ------------------------------------------------------------------ zero bucket hist
__global__ void k_zerob(int* __restrict__ gbh) {
    int i = blockIdx.x * blockDim.x + threadIdx.x;
    if (i < NBKT) gbh[i] = 0;
}

// ------------------------------------------------------------------ bucket histogram (LDS-local)
__global__ __launch_bounds__(256) void k_bhist(const int* __restrict__ ei,
                                               int* __restrict__ gbh, int nE) {
    __shared__ int h[NBKT];
    const int tid = threadIdx.x;
    for (int i = tid; i < NBKT; i += 256) h[i] = 0;
    __syncthreads();
    const int per = (nE + gridDim.x - 1) / gridDim.x;
    const int e0 = blockIdx.x * per;
    const int e1 = min(e0 + per, nE);
    for (int e = e0 + tid; e < e1; e += 256)
        atomicAdd(&h[ei[nE + e] >> 7], 1);
    __syncthreads();
    for (int i = tid; i < NBKT; i += 256)
        if (h[i]) atomicAdd(&gbh[i], h[i]);
}

// ------------------------------------------------------------------ bucket scan (16-padded bases)
__global__ __launch_bounds__(1024) void k_bscan(const int* __restrict__ gbh,
                                                int* __restrict__ bbase,
                                                int* __restrict__ gcur) {
    __shared__ int ws[16];
    const int tid = threadIdx.x, lane = tid & 63, wid = tid >> 6;
    int v = 0;
    if (tid < NBKT) v = (gbh[tid] + 15) & ~15;      // pad to 16 -> 64B-aligned bases
    int s = v;
#pragma unroll
    for (int d = 1; d < 64; d <<= 1) { int t = __shfl_up(s, d, 64); if (lane >= d) s += t; }
    if (lane == 63) ws[wid] = s;
    __syncthreads();
    if (tid < 16) {
        int wv = ws[tid];
        int ps = wv;
#pragma unroll
        for (int d = 1; d < 16; d <<= 1) { int t = __shfl_up(ps, d, 16); if (tid >= d) ps += t; }
        ws[tid] = ps;                                // inclusive
    }
    __syncthreads();
    int excl = ((wid == 0) ? 0 : ws[wid - 1]) + (s - v);
    if (tid < NBKT) { bbase[tid] = excl; gcur[tid] = excl; }
}

// ------------------------------------------------------------------ LDS-staged partition (proven in r4)
// Packs src<<7 | (dst&127); flushes 16-entry (64B) groups -> no write amplification.
__global__ __launch_bounds__(256, 2) void k_part(const int* __restrict__ ei,
                                                 int* __restrict__ gcur,
                                                 unsigned* __restrict__ pedges, int nE) {
    __shared__ unsigned buf[NBKT][BCAP];     // 50 KB
    __shared__ int bcnt[NBKT];
    __shared__ unsigned rpk[256];
    __shared__ int rbk[256];
    __shared__ int rcnt;
    const int tid = threadIdx.x;
    for (int i = tid; i < NBKT; i += 256) bcnt[i] = 0;
    if (tid == 0) rcnt = 0;
    __syncthreads();
    const int per = (nE + gridDim.x - 1) / gridDim.x;
    const int e0 = blockIdx.x * per;
    const int e1 = min(e0 + per, nE);
    for (int base = e0; base < e1; base += 256) {
        const int e = base + tid;
        if (e < e1) {
            int src = ei[e];
            int dst = ei[nE + e];
            int b = dst >> 7;
            unsigned pk = ((unsigned)src << 7) | (unsigned)(dst & 127);
            int pos = atomicAdd(&bcnt[b], 1);
            if (pos < BCAP) buf[b][pos] = pk;
            else { int r = atomicAdd(&rcnt, 1); rpk[r] = pk; rbk[r] = b; }
        }
        __syncthreads();
        while (true) {
            for (int bb = tid; bb < NBKT; bb += 256) {
                if (bcnt[bb] >= BCAP) {
                    int gp = atomicAdd(&gcur[bb], BCAP);
#pragma unroll
                    for (int i = 0; i < BCAP; ++i) pedges[gp + i] = buf[bb][i];
                    bcnt[bb] = 0;
                }
            }
            __syncthreads();
            int nr = rcnt;
            unsigned mpk = 0; int mb = -1;
            if (tid < nr) { mpk = rpk[tid]; mb = rbk[tid]; }
            __syncthreads();
            if (nr == 0) break;
            if (tid == 0) rcnt = 0;
            __syncthreads();
            if (mb >= 0) {
                int pos = atomicAdd(&bcnt[mb], 1);
                if (pos < BCAP) buf[mb][pos] = mpk;
                else { int r = atomicAdd(&rcnt, 1); rpk[r] = mpk; rbk[r] = mb; }
            }
            __syncthreads();
        }
    }
    for (int bb = tid; bb < NBKT; bb += 256) {
        int c = bcnt[bb];
        if (c > 0) {
            int gp = atomicAdd(&gcur[bb], c);
            for (int i = 0; i < c; ++i) pedges[gp + i] = buf[bb][i];
        }
    }
}

// ------------------------------------------------------------------ GEMM1: yz = x(bf16) . Wc^T
// yz[n][0:64] = x.Wl^T (y, gathered later); yz[n][64:128] = x.Wr^T (z).
// One wave per 64 nodes; x converted to bf16 in-register (no xb buffer).
__global__ __launch_bounds__(64) void k_gemm1(const float* __restrict__ x,
                                              const unsigned short* __restrict__ Wc,
                                              unsigned short* __restrict__ yz) {
    const int nb = blockIdx.x * 64;
    const int lane = threadIdx.x;
    const int lm = lane & 15, lk = lane >> 4;

    f32x4 acc[4][8];
#pragma unroll
    for (int a = 0; a < 4; ++a)
#pragma unroll
        for (int b = 0; b < 8; ++b) acc[a][b] = f32x4{0.f, 0.f, 0.f, 0.f};

#pragma unroll
    for (int kt = 0; kt < 4; ++kt) {
        const int ko = kt * 32 + lk * 8;
        bf8 af[4], bw[8];
#pragma unroll
        for (int mt = 0; mt < 4; ++mt) {
            int row = nb + mt * 16 + lm;
            if (row >= N_NODES) row = N_NODES - 1;
            const float* xp = x + (size_t)row * F_IN + ko;
            float4 v0 = *(const float4*)xp;
            float4 v1 = *(const float4*)(xp + 4);
            bf8 t;
            t[0] = (short)f2bf(v0.x); t[1] = (short)f2bf(v0.y);
            t[2] = (short)f2bf(v0.z); t[3] = (short)f2bf(v0.w);
            t[4] = (short)f2bf(v1.x); t[5] = (short)f2bf(v1.y);
            t[6] = (short)f2bf(v1.z); t[7] = (short)f2bf(v1.w);
            af[mt] = t;
        }
#pragma unroll
        for (int nt = 0; nt < 8; ++nt)
            bw[nt] = *reinterpret_cast<const bf8*>(Wc + (nt * 16 + lm) * 128 + ko);
#pragma unroll
        for (int mt = 0; mt < 4; ++mt)
#pragma unroll
            for (int nt = 0; nt < 8; ++nt)
                acc[mt][nt] = __builtin_amdgcn_mfma_f32_16x16x32_bf16(af[mt], bw[nt], acc[mt][nt], 0, 0, 0);
    }
#pragma unroll
    for (int mt = 0; mt < 4; ++mt)
#pragma unroll
        for (int r = 0; r < 4; ++r) {
            int node = nb + mt * 16 + lk * 4 + r;
            if (node < N_NODES) {
#pragma unroll
                for (int nt = 0; nt < 8; ++nt)
                    yz[(size_t)node * 128 + nt * 16 + lm] = f2bf(acc[mt][nt][r]);
            }
        }
}

// ------------------------------------------------------------------ bucket agg in y-space
// One block (4 waves) per 128-node bucket: counting-sort edges in LDS, then
// wave-per-node gather of 128B y-rows (L2/L3-resident 12.8MB table).
__global__ __launch_bounds__(256) void k_agg3(const unsigned short* __restrict__ yz,
                                              const unsigned* __restrict__ pedges,
                                              const int* __restrict__ bbase,
                                              const int* __restrict__ gbh,
                                              unsigned short* __restrict__ aggY) {
    __shared__ unsigned esrc[ECAP];          // 10.5 KB
    __shared__ int hcnt[128], hoff[128], hcur[128];
    const int tid = threadIdx.x, lane = tid & 63, wv = tid >> 6;
    const int bkt = blockIdx.x;
    int cnt = gbh[bkt]; if (cnt > ECAP) cnt = ECAP;
    const int base = bbase[bkt];
    if (tid < 128) hcnt[tid] = 0;
    __syncthreads();
    // pass 1: local histogram (pedges segment is L2-hot for pass 2)
    for (int i = tid; i < cnt; i += 256)
        atomicAdd(&hcnt[pedges[base + i] & 127], 1);
    __syncthreads();
    // exclusive scan of 128 bins (one wave, pair-per-lane)
    if (tid < 64) {
        int a = hcnt[2 * tid], b = hcnt[2 * tid + 1];
        int s = a + b;
#pragma unroll
        for (int d = 1; d < 64; d <<= 1) { int t = __shfl_up(s, d, 64); if (lane >= d) s += t; }
        int ex = s - (a + b);
        hoff[2 * tid] = ex;     hcur[2 * tid] = ex;
        hoff[2 * tid + 1] = ex + a; hcur[2 * tid + 1] = ex + a;
    }
    __syncthreads();
    // pass 2: scatter srcs into per-node-sorted LDS array
    for (int i = tid; i < cnt; i += 256) {
        unsigned e = pedges[base + i];
        int p = atomicAdd(&hcur[e & 127], 1);
        esrc[p] = e >> 7;
    }
    __syncthreads();
    // gather: wave per node, lane owns 1 of 64 y-features
    for (int loc = wv; loc < 128; loc += 4) {
        int node = bkt * 128 + loc;
        if (node >= N_NODES) break;
        int st = hoff[loc], dg = hcnt[loc];
        float a = 0.f;
        int j = 0;
        for (; j + 4 <= dg; j += 4) {
            unsigned s0 = esrc[st + j + 0];
            unsigned s1 = esrc[st + j + 1];
            unsigned s2 = esrc[st + j + 2];
            unsigned s3 = esrc[st + j + 3];
            float v0 = b2f(yz[(size_t)s0 * 128 + lane]);
            float v1 = b2f(yz[(size_t)s1 * 128 + lane]);
            float v2 = b2f(yz[(size_t)s2 * 128 + lane]);
            float v3 = b2f(yz[(size_t)s3 * 128 + lane]);
            a += v0 + v1 + v2 + v3;
        }
        for (; j < dg; ++j)
            a += b2f(yz[(size_t)esrc[st + j] * 128 + lane]);
        float inv = 1.0f / fmaxf((float)dg, 1.0f);
        aggY[(size_t)node * HID + lane] = f2bf(a * inv);
    }
}

// ------------------------------------------------------------------ fused2: h = relu(aggY+z+bl); out = h.Wo^T + bout
// h fragments built directly from memory (no LDS transpose needed).
__global__ __launch_bounds__(64) void k_fused2(
    const unsigned short* __restrict__ aggY, const unsigned short* __restrict__ yz,
    const float* __restrict__ bl, const unsigned short* __restrict__ Wo,
    const float* __restrict__ bout, float* __restrict__ out) {

    const int nb = blockIdx.x * 64;
    const int lane = threadIdx.x;
    const int lm = lane & 15, lk = lane >> 4;

    bf8 ah[4][2];
#pragma unroll
    for (int mt = 0; mt < 4; ++mt) {
        int row = nb + mt * 16 + lm;
        if (row >= N_NODES) row = N_NODES - 1;
#pragma unroll
        for (int k2 = 0; k2 < 2; ++k2) {
            int kb = k2 * 32 + lk * 8;
            bf8 av = *reinterpret_cast<const bf8*>(aggY + (size_t)row * HID + kb);
            bf8 zv = *reinterpret_cast<const bf8*>(yz + (size_t)row * 128 + HID + kb);
            float4 b0 = *(const float4*)(bl + kb);
            float4 b1 = *(const float4*)(bl + kb + 4);
            float bb[8] = {b0.x, b0.y, b0.z, b0.w, b1.x, b1.y, b1.z, b1.w};
            bf8 t;
#pragma unroll
            for (int j = 0; j < 8; ++j) {
                float v = b2f((unsigned short)av[j]) + b2f((unsigned short)zv[j]) + bb[j];
                t[j] = (short)f2bf(fmaxf(v, 0.f));
            }
            ah[mt][k2] = t;
        }
    }

    for (int g = 0; g < 5; ++g) {
        f32x4 acc2[4][4];
#pragma unroll
        for (int a = 0; a < 4; ++a)
#pragma unroll
            for (int b = 0; b < 4; ++b) acc2[a][b] = f32x4{0.f, 0.f, 0.f, 0.f};
#pragma unroll
        for (int k2 = 0; k2 < 2; ++k2) {
            bf8 bw[4];
#pragma unroll
            for (int nt = 0; nt < 4; ++nt)
                bw[nt] = *reinterpret_cast<const bf8*>(
                    Wo + (size_t)((g * 4 + nt) * 16 + lm) * HID + k2 * 32 + lk * 8);
#pragma unroll
            for (int mt = 0; mt < 4; ++mt)
#pragma unroll
                for (int nt = 0; nt < 4; ++nt)
                    acc2[mt][nt] = __builtin_amdgcn_mfma_f32_16x16x32_bf16(ah[mt][k2], bw[nt], acc2[mt][nt], 0, 0, 0);
        }
#pragma unroll
        for (int nt = 0; nt < 4; ++nt) {
            int o = (g * 4 + nt) * 16 + lm;
            float bo = (o < OUT_F) ? bout[o] : 0.f;
#pragma unroll
            for (int mt = 0; mt < 4; ++mt)
#pragma unroll
                for (int r = 0; r < 4; ++r) {
                    int node = nb + mt * 16 + lk * 4 + r;
                    if (node < N_NODES && o < OUT_F)
                        out[(size_t)node * OUT_F + o] = acc2[mt][nt][r] + bo;
                }
        }
    }
}

extern "C" void kernel_launch(void* const* d_in, const int* in_sizes, int n_in,
                              void* d_out, int out_size, void* d_ws, size_t ws_size,
                              hipStream_t stream) {
    const float* x    = (const float*)d_in[0];
    const int*   ei   = (const int*)d_in[1];
    const float* Wl   = (const float*)d_in[2];
    const float* bl   = (const float*)d_in[3];
    const float* Wr   = (const float*)d_in[4];
    const float* Wout = (const float*)d_in[5];
    const float* bout = (const float*)d_in[6];
    float* out = (float*)d_out;

    int nE = in_sizes[1] / 2;

    unsigned short* yz   = (unsigned short*)d_ws;                 // 25.6 MB
    unsigned short* aggY = yz + (size_t)N_NODES * 128;            // 12.8 MB
    unsigned* pedges = (unsigned*)(aggY + (size_t)N_NODES * HID); // 6.48 MB
    int* gbh   = (int*)(pedges + 1620000);
    int* bbase = gbh + NBKT;
    int* gcur  = bbase + NBKT;
    unsigned short* Wc = (unsigned short*)(gcur + NBKT);          // 128*128
    unsigned short* Wo = Wc + 128 * 128;                          // 320*64

    k_wcvt<<<(128 * 128 + WO_ROWS * HID + 255) / 256, 256, 0, stream>>>(Wl, Wr, Wout, Wc, Wo);
    k_zerob<<<(NBKT + 255) / 256, 256, 0, stream>>>(gbh);
    k_bhist<<<512, 256, 0, stream>>>(ei, gbh, nE);
    k_bscan<<<1, 1024, 0, stream>>>(gbh, bbase, gcur);
    k_part<<<512, 256, 0, stream>>>(ei, gcur, pedges, nE);
    k_gemm1<<<(N_NODES + 63) / 64, 64, 0, stream>>>(x, Wc, yz);
    k_agg3<<<NBKT, 256, 0, stream>>>(yz, pedges, bbase, gbh, aggY);
    k_fused2<<<(N_NODES + 63) / 64, 64, 0, stream>>>(aggY, yz, bl, Wo, bout, out);
}

// Round 6
// 210.316 us; speedup vs baseline: 7.2506x; 1.0078x over previous
//
#include <hip/hip_runtime.h>

#define N_NODES 100000
#define F_IN 128
#define HID 64
#define OUT_F 300
#define WO_ROWS 320         // 300 padded to 20 tiles of 16
#define NBKT 782            // ceil(100000 / 128) buckets of 128 nodes
#define BCAP 16             // k_part staging slots per bucket (flush = 64B)
#define ECAP 2688           // per-bucket edge cap (mean 2046, sigma 45 -> +14 sigma)

typedef short bf8 __attribute__((ext_vector_type(8)));
typedef float f32x4 __attribute__((ext_vector_type(4)));

__device__ inline unsigned short f2bf(float f) {
    unsigned u = __builtin_bit_cast(unsigned, f);
    u += 0x7fff + ((u >> 16) & 1);          // round-to-nearest-even
    return (unsigned short)(u >> 16);
}
__device__ inline float b2f(unsigned short h) {
    return __builtin_bit_cast(float, (unsigned)h << 16);
}

// ------------------------------------------------------------------ prep: weights->bf16 + zero hist
__global__ void k_prep(const float* __restrict__ Wl, const float* __restrict__ Wr,
                       const float* __restrict__ Wout,
                       unsigned short* __restrict__ Wc, unsigned short* __restrict__ Wo,
                       int* __restrict__ gbh) {
    int idx = blockIdx.x * blockDim.x + threadIdx.x;
    if (idx < 128 * 128) {
        int c = idx >> 7, k = idx & 127;
        float v = (c < HID) ? Wl[c * F_IN + k] : Wr[(c - HID) * F_IN + k];
        Wc[idx] = f2bf(v);
    } else if (idx < 128 * 128 + WO_ROWS * HID) {
        int j = idx - 128 * 128;
        int o = j >> 6, k = j & 63;
        Wo[j] = (o < OUT_F) ? f2bf(Wout[o * HID + k]) : (unsigned short)0;
    } else {
        int b = idx - 128 * 128 - WO_ROWS * HID;
        if (b < NBKT) gbh[b] = 0;
    }
}

// ------------------------------------------------------------------ bucket histogram (LDS-local)
__global__ __launch_bounds__(256) void k_bhist(const int* __restrict__ ei,
                                               int* __restrict__ gbh, int nE) {
    __shared__ int h[NBKT];
    const int tid = threadIdx.x;
    for (int i = tid; i < NBKT; i += 256) h[i] = 0;
    __syncthreads();
    const int per = (nE + gridDim.x - 1) / gridDim.x;
    const int e0 = blockIdx.x * per;
    const int e1 = min(e0 + per, nE);
    for (int e = e0 + tid; e < e1; e += 256)
        atomicAdd(&h[ei[nE + e] >> 7], 1);
    __syncthreads();
    for (int i = tid; i < NBKT; i += 256)
        if (h[i]) atomicAdd(&gbh[i], h[i]);
}

// ------------------------------------------------------------------ bucket scan (16-padded bases)
__global__ __launch_bounds__(1024) void k_bscan(const int* __restrict__ gbh,
                                                int* __restrict__ bbase,
                                                int* __restrict__ gcur) {
    __shared__ int ws[16];
    const int tid = threadIdx.x, lane = tid & 63, wid = tid >> 6;
    int v = 0;
    if (tid < NBKT) v = (gbh[tid] + 15) & ~15;      // pad to 16 -> 64B-aligned bases
    int s = v;
#pragma unroll
    for (int d = 1; d < 64; d <<= 1) { int t = __shfl_up(s, d, 64); if (lane >= d) s += t; }
    if (lane == 63) ws[wid] = s;
    __syncthreads();
    if (tid < 16) {
        int wv = ws[tid];
        int ps = wv;
#pragma unroll
        for (int d = 1; d < 16; d <<= 1) { int t = __shfl_up(ps, d, 16); if (tid >= d) ps += t; }
        ws[tid] = ps;                                // inclusive
    }
    __syncthreads();
    int excl = ((wid == 0) ? 0 : ws[wid - 1]) + (s - v);
    if (tid < NBKT) { bbase[tid] = excl; gcur[tid] = excl; }
}

// ------------------------------------------------------------------ LDS-staged partition (proven r4/r5)
// Packs src<<7 | (dst&127); flushes 16-entry (64B) groups -> no write amplification.
__global__ __launch_bounds__(256, 2) void k_part(const int* __restrict__ ei,
                                                 int* __restrict__ gcur,
                                                 unsigned* __restrict__ pedges, int nE) {
    __shared__ unsigned buf[NBKT][BCAP];     // 50 KB
    __shared__ int bcnt[NBKT];
    __shared__ unsigned rpk[256];
    __shared__ int rbk[256];
    __shared__ int rcnt;
    const int tid = threadIdx.x;
    for (int i = tid; i < NBKT; i += 256) bcnt[i] = 0;
    if (tid == 0) rcnt = 0;
    __syncthreads();
    const int per = (nE + gridDim.x - 1) / gridDim.x;
    const int e0 = blockIdx.x * per;
    const int e1 = min(e0 + per, nE);
    for (int base = e0; base < e1; base += 256) {
        const int e = base + tid;
        if (e < e1) {
            int src = ei[e];
            int dst = ei[nE + e];
            int b = dst >> 7;
            unsigned pk = ((unsigned)src << 7) | (unsigned)(dst & 127);
            int pos = atomicAdd(&bcnt[b], 1);
            if (pos < BCAP) buf[b][pos] = pk;
            else { int r = atomicAdd(&rcnt, 1); rpk[r] = pk; rbk[r] = b; }
        }
        __syncthreads();
        while (true) {
            for (int bb = tid; bb < NBKT; bb += 256) {
                if (bcnt[bb] >= BCAP) {
                    int gp = atomicAdd(&gcur[bb], BCAP);
#pragma unroll
                    for (int i = 0; i < BCAP; ++i) pedges[gp + i] = buf[bb][i];
                    bcnt[bb] = 0;
                }
            }
            __syncthreads();
            int nr = rcnt;
            unsigned mpk = 0; int mb = -1;
            if (tid < nr) { mpk = rpk[tid]; mb = rbk[tid]; }
            __syncthreads();
            if (nr == 0) break;
            if (tid == 0) rcnt = 0;
            __syncthreads();
            if (mb >= 0) {
                int pos = atomicAdd(&bcnt[mb], 1);
                if (pos < BCAP) buf[mb][pos] = mpk;
                else { int r = atomicAdd(&rcnt, 1); rpk[r] = mpk; rbk[r] = mb; }
            }
            __syncthreads();
        }
    }
    for (int bb = tid; bb < NBKT; bb += 256) {
        int c = bcnt[bb];
        if (c > 0) {
            int gp = atomicAdd(&gcur[bb], c);
            for (int i = 0; i < c; ++i) pedges[gp + i] = buf[bb][i];
        }
    }
}

// ------------------------------------------------------------------ GEMM1: yz = x(bf16) . Wc^T
// yz[n][0:64] = x.Wl^T (y, gathered later); yz[n][64:128] = x.Wr^T (z).
__global__ __launch_bounds__(64) void k_gemm1(const float* __restrict__ x,
                                              const unsigned short* __restrict__ Wc,
                                              unsigned short* __restrict__ yz) {
    const int nb = blockIdx.x * 64;
    const int lane = threadIdx.x;
    const int lm = lane & 15, lk = lane >> 4;

    f32x4 acc[4][8];
#pragma unroll
    for (int a = 0; a < 4; ++a)
#pragma unroll
        for (int b = 0; b < 8; ++b) acc[a][b] = f32x4{0.f, 0.f, 0.f, 0.f};

#pragma unroll
    for (int kt = 0; kt < 4; ++kt) {
        const int ko = kt * 32 + lk * 8;
        bf8 af[4], bw[8];
#pragma unroll
        for (int mt = 0; mt < 4; ++mt) {
            int row = nb + mt * 16 + lm;
            if (row >= N_NODES) row = N_NODES - 1;
            const float* xp = x + (size_t)row * F_IN + ko;
            float4 v0 = *(const float4*)xp;
            float4 v1 = *(const float4*)(xp + 4);
            bf8 t;
            t[0] = (short)f2bf(v0.x); t[1] = (short)f2bf(v0.y);
            t[2] = (short)f2bf(v0.z); t[3] = (short)f2bf(v0.w);
            t[4] = (short)f2bf(v1.x); t[5] = (short)f2bf(v1.y);
            t[6] = (short)f2bf(v1.z); t[7] = (short)f2bf(v1.w);
            af[mt] = t;
        }
#pragma unroll
        for (int nt = 0; nt < 8; ++nt)
            bw[nt] = *reinterpret_cast<const bf8*>(Wc + (nt * 16 + lm) * 128 + ko);
#pragma unroll
        for (int mt = 0; mt < 4; ++mt)
#pragma unroll
            for (int nt = 0; nt < 8; ++nt)
                acc[mt][nt] = __builtin_amdgcn_mfma_f32_16x16x32_bf16(af[mt], bw[nt], acc[mt][nt], 0, 0, 0);
    }
#pragma unroll
    for (int mt = 0; mt < 4; ++mt)
#pragma unroll
        for (int r = 0; r < 4; ++r) {
            int node = nb + mt * 16 + lk * 4 + r;
            if (node < N_NODES) {
#pragma unroll
                for (int nt = 0; nt < 8; ++nt)
                    yz[(size_t)node * 128 + nt * 16 + lm] = f2bf(acc[mt][nt][r]);
            }
        }
}

// ------------------------------------------------------------------ bucket agg in y-space + h-formation
// One block (4 waves) per 128-node bucket: counting-sort edges in LDS, then
// wave-per-node gather of 128B y-rows; epilogue h = relu(mean + z + bl) (bf16).
__global__ __launch_bounds__(256) void k_agg3(const unsigned short* __restrict__ yz,
                                              const unsigned* __restrict__ pedges,
                                              const int* __restrict__ bbase,
                                              const int* __restrict__ gbh,
                                              const float* __restrict__ bl,
                                              unsigned short* __restrict__ h) {
    __shared__ unsigned esrc[ECAP];          // 10.5 KB
    __shared__ int hcnt[128], hoff[128], hcur[128];
    const int tid = threadIdx.x, lane = tid & 63, wv = tid >> 6;
    const int bkt = blockIdx.x;
    int cnt = gbh[bkt]; if (cnt > ECAP) cnt = ECAP;
    const int base = bbase[bkt];
    if (tid < 128) hcnt[tid] = 0;
    __syncthreads();
    for (int i = tid; i < cnt; i += 256)
        atomicAdd(&hcnt[pedges[base + i] & 127], 1);
    __syncthreads();
    if (tid < 64) {
        int a = hcnt[2 * tid], b = hcnt[2 * tid + 1];
        int s = a + b;
#pragma unroll
        for (int d = 1; d < 64; d <<= 1) { int t = __shfl_up(s, d, 64); if (lane >= d) s += t; }
        int ex = s - (a + b);
        hoff[2 * tid] = ex;     hcur[2 * tid] = ex;
        hoff[2 * tid + 1] = ex + a; hcur[2 * tid + 1] = ex + a;
    }
    __syncthreads();
    for (int i = tid; i < cnt; i += 256) {
        unsigned e = pedges[base + i];
        int p = atomicAdd(&hcur[e & 127], 1);
        esrc[p] = e >> 7;
    }
    __syncthreads();
    float blv = bl[lane];
    for (int loc = wv; loc < 128; loc += 4) {
        int node = bkt * 128 + loc;
        if (node >= N_NODES) break;
        int st = hoff[loc], dg = hcnt[loc];
        float a = 0.f;
        int j = 0;
        for (; j + 4 <= dg; j += 4) {
            unsigned s0 = esrc[st + j + 0];
            unsigned s1 = esrc[st + j + 1];
            unsigned s2 = esrc[st + j + 2];
            unsigned s3 = esrc[st + j + 3];
            float v0 = b2f(yz[(size_t)s0 * 128 + lane]);
            float v1 = b2f(yz[(size_t)s1 * 128 + lane]);
            float v2 = b2f(yz[(size_t)s2 * 128 + lane]);
            float v3 = b2f(yz[(size_t)s3 * 128 + lane]);
            a += v0 + v1 + v2 + v3;
        }
        for (; j < dg; ++j)
            a += b2f(yz[(size_t)esrc[st + j] * 128 + lane]);
        float inv = 1.0f / fmaxf((float)dg, 1.0f);
        float z = b2f(yz[(size_t)node * 128 + HID + lane]);
        float v = a * inv + z + blv;
        h[(size_t)node * HID + lane] = f2bf(fmaxf(v, 0.f));
    }
}

// ------------------------------------------------------------------ fused2: out = h.Wo^T + bout
// 256 threads / 64 nodes; wave = 16 nodes x 300 outs; full fp32 tile staged in
// 75KB LDS then written as one contiguous, line-aligned 76800B block.
__global__ __launch_bounds__(256, 2) void k_fused2(
    const unsigned short* __restrict__ h, const unsigned short* __restrict__ Wo,
    const float* __restrict__ bout, float* __restrict__ out) {

    __shared__ float sout[64 * OUT_F];       // 75 KB
    const int tid = threadIdx.x;
    const int lane = tid & 63;
    const int mt = tid >> 6;                 // wave id = 16-node group
    const int nb = blockIdx.x * 64;
    const int lm = lane & 15, lk = lane >> 4;

    int row = nb + mt * 16 + lm;
    if (row >= N_NODES) row = N_NODES - 1;
    bf8 ah[2];
#pragma unroll
    for (int k2 = 0; k2 < 2; ++k2)
        ah[k2] = *reinterpret_cast<const bf8*>(h + (size_t)row * HID + k2 * 32 + lk * 8);

    for (int g = 0; g < 5; ++g) {
        f32x4 acc2[4];
#pragma unroll
        for (int b = 0; b < 4; ++b) acc2[b] = f32x4{0.f, 0.f, 0.f, 0.f};
#pragma unroll
        for (int k2 = 0; k2 < 2; ++k2) {
            bf8 bw[4];
#pragma unroll
            for (int nt = 0; nt < 4; ++nt)
                bw[nt] = *reinterpret_cast<const bf8*>(
                    Wo + (size_t)((g * 4 + nt) * 16 + lm) * HID + k2 * 32 + lk * 8);
#pragma unroll
            for (int nt = 0; nt < 4; ++nt)
                acc2[nt] = __builtin_amdgcn_mfma_f32_16x16x32_bf16(ah[k2], bw[nt], acc2[nt], 0, 0, 0);
        }
#pragma unroll
        for (int nt = 0; nt < 4; ++nt) {
            int o = g * 64 + nt * 16 + lm;
            if (o < OUT_F) {
                float bo = bout[o];
#pragma unroll
                for (int r = 0; r < 4; ++r) {
                    int locn = mt * 16 + lk * 4 + r;
                    sout[locn * OUT_F + o] = acc2[nt][r] + bo;
                }
            }
        }
    }
    __syncthreads();
    const int nvalid = min(64, N_NODES - nb);
    const int total = nvalid * OUT_F;
    float* op = out + (size_t)nb * OUT_F;
    for (int i = tid; i < total; i += 256) op[i] = sout[i];
}

extern "C" void kernel_launch(void* const* d_in, const int* in_sizes, int n_in,
                              void* d_out, int out_size, void* d_ws, size_t ws_size,
                              hipStream_t stream) {
    const float* x    = (const float*)d_in[0];
    const int*   ei   = (const int*)d_in[1];
    const float* Wl   = (const float*)d_in[2];
    const float* bl   = (const float*)d_in[3];
    const float* Wr   = (const float*)d_in[4];
    const float* Wout = (const float*)d_in[5];
    const float* bout = (const float*)d_in[6];
    float* out = (float*)d_out;

    int nE = in_sizes[1] / 2;

    unsigned short* yz = (unsigned short*)d_ws;                   // 25.6 MB
    unsigned short* h  = yz + (size_t)N_NODES * 128;              // 12.8 MB
    unsigned* pedges = (unsigned*)(h + (size_t)N_NODES * HID);    // 6.48 MB
    int* gbh   = (int*)(pedges + 1620000);
    int* bbase = gbh + NBKT;
    int* gcur  = bbase + NBKT;
    unsigned short* Wc = (unsigned short*)(gcur + NBKT);          // 128*128
    unsigned short* Wo = Wc + 128 * 128;                          // 320*64

    int prep_n = 128 * 128 + WO_ROWS * HID + NBKT;
    k_prep<<<(prep_n + 255) / 256, 256, 0, stream>>>(Wl, Wr, Wout, Wc, Wo, gbh);
    k_bhist<<<512, 256, 0, stream>>>(ei, gbh, nE);
    k_bscan<<<1, 1024, 0, stream>>>(gbh, bbase, gcur);
    k_part<<<512, 256, 0, stream>>>(ei, gcur, pedges, nE);
    k_gemm1<<<(N_NODES + 63) / 64, 64, 0, stream>>>(x, Wc, yz);
    k_agg3<<<NBKT, 256, 0, stream>>>(yz, pedges, bbase, gbh, bl, h);
    k_fused2<<<(N_NODES + 63) / 64, 256, 0, stream>>>(h, Wo, bout, out);
}

// Round 7
// 184.617 us; speedup vs baseline: 8.2599x; 1.1392x over previous
//
#include <hip/hip_runtime.h>

#define N_NODES 100000
#define F_IN 128
#define HID 64
#define OUT_F 300
#define WO_ROWS 320         // 300 padded to 20 tiles of 16
#define NBKT 782            // ceil(100000 / 128) buckets of 128 nodes
#define BCAP 16             // k_part staging slots per bucket (flush = 64B)
#define ECAP 2688           // per-bucket edge cap (mean 2046, sigma 45 -> +14 sigma)

typedef short bf8 __attribute__((ext_vector_type(8)));
typedef float f32x4 __attribute__((ext_vector_type(4)));

__device__ inline unsigned short f2bf(float f) {
    unsigned u = __builtin_bit_cast(unsigned, f);
    u += 0x7fff + ((u >> 16) & 1);          // round-to-nearest-even
    return (unsigned short)(u >> 16);
}
__device__ inline float b2f(unsigned short h) {
    return __builtin_bit_cast(float, (unsigned)h << 16);
}

// ------------------------------------------------------------------ prep: weights->bf16 + zero hist
__global__ void k_prep(const float* __restrict__ Wl, const float* __restrict__ Wr,
                       const float* __restrict__ Wout,
                       unsigned short* __restrict__ Wc, unsigned short* __restrict__ Wo,
                       int* __restrict__ gbh) {
    int idx = blockIdx.x * blockDim.x + threadIdx.x;
    if (idx < 128 * 128) {
        int c = idx >> 7, k = idx & 127;
        float v = (c < HID) ? Wl[c * F_IN + k] : Wr[(c - HID) * F_IN + k];
        Wc[idx] = f2bf(v);
    } else if (idx < 128 * 128 + WO_ROWS * HID) {
        int j = idx - 128 * 128;
        int o = j >> 6, k = j & 63;
        Wo[j] = (o < OUT_F) ? f2bf(Wout[o * HID + k]) : (unsigned short)0;
    } else {
        int b = idx - 128 * 128 - WO_ROWS * HID;
        if (b < NBKT) gbh[b] = 0;
    }
}

// ------------------------------------------------------------------ bucket histogram (LDS-local)
__global__ __launch_bounds__(256) void k_bhist(const int* __restrict__ ei,
                                               int* __restrict__ gbh, int nE) {
    __shared__ int h[NBKT];
    const int tid = threadIdx.x;
    for (int i = tid; i < NBKT; i += 256) h[i] = 0;
    __syncthreads();
    const int per = (nE + gridDim.x - 1) / gridDim.x;
    const int e0 = blockIdx.x * per;
    const int e1 = min(e0 + per, nE);
    for (int e = e0 + tid; e < e1; e += 256)
        atomicAdd(&h[ei[nE + e] >> 7], 1);
    __syncthreads();
    for (int i = tid; i < NBKT; i += 256)
        if (h[i]) atomicAdd(&gbh[i], h[i]);
}

// ------------------------------------------------------------------ bucket scan (16-padded bases)
__global__ __launch_bounds__(1024) void k_bscan(const int* __restrict__ gbh,
                                                int* __restrict__ bbase,
                                                int* __restrict__ gcur) {
    __shared__ int ws[16];
    const int tid = threadIdx.x, lane = tid & 63, wid = tid >> 6;
    int v = 0;
    if (tid < NBKT) v = (gbh[tid] + 15) & ~15;      // pad to 16 -> 64B-aligned bases
    int s = v;
#pragma unroll
    for (int d = 1; d < 64; d <<= 1) { int t = __shfl_up(s, d, 64); if (lane >= d) s += t; }
    if (lane == 63) ws[wid] = s;
    __syncthreads();
    if (tid < 16) {
        int wv = ws[tid];
        int ps = wv;
#pragma unroll
        for (int d = 1; d < 16; d <<= 1) { int t = __shfl_up(ps, d, 16); if (tid >= d) ps += t; }
        ws[tid] = ps;                                // inclusive
    }
    __syncthreads();
    int excl = ((wid == 0) ? 0 : ws[wid - 1]) + (s - v);
    if (tid < NBKT) { bbase[tid] = excl; gcur[tid] = excl; }
}

// ------------------------------------------------------------------ LDS-staged partition (proven r4-r6)
// Packs src<<7 | (dst&127); flushes 16-entry (64B) groups -> no write amplification.
__global__ __launch_bounds__(256, 2) void k_part(const int* __restrict__ ei,
                                                 int* __restrict__ gcur,
                                                 unsigned* __restrict__ pedges, int nE) {
    __shared__ unsigned buf[NBKT][BCAP];     // 50 KB
    __shared__ int bcnt[NBKT];
    __shared__ unsigned rpk[256];
    __shared__ int rbk[256];
    __shared__ int rcnt;
    const int tid = threadIdx.x;
    for (int i = tid; i < NBKT; i += 256) bcnt[i] = 0;
    if (tid == 0) rcnt = 0;
    __syncthreads();
    const int per = (nE + gridDim.x - 1) / gridDim.x;
    const int e0 = blockIdx.x * per;
    const int e1 = min(e0 + per, nE);
    for (int base = e0; base < e1; base += 256) {
        const int e = base + tid;
        if (e < e1) {
            int src = ei[e];
            int dst = ei[nE + e];
            int b = dst >> 7;
            unsigned pk = ((unsigned)src << 7) | (unsigned)(dst & 127);
            int pos = atomicAdd(&bcnt[b], 1);
            if (pos < BCAP) buf[b][pos] = pk;
            else { int r = atomicAdd(&rcnt, 1); rpk[r] = pk; rbk[r] = b; }
        }
        __syncthreads();
        while (true) {
            for (int bb = tid; bb < NBKT; bb += 256) {
                if (bcnt[bb] >= BCAP) {
                    int gp = atomicAdd(&gcur[bb], BCAP);
#pragma unroll
                    for (int i = 0; i < BCAP; ++i) pedges[gp + i] = buf[bb][i];
                    bcnt[bb] = 0;
                }
            }
            __syncthreads();
            int nr = rcnt;
            unsigned mpk = 0; int mb = -1;
            if (tid < nr) { mpk = rpk[tid]; mb = rbk[tid]; }
            __syncthreads();
            if (nr == 0) break;
            if (tid == 0) rcnt = 0;
            __syncthreads();
            if (mb >= 0) {
                int pos = atomicAdd(&bcnt[mb], 1);
                if (pos < BCAP) buf[mb][pos] = mpk;
                else { int r = atomicAdd(&rcnt, 1); rpk[r] = mpk; rbk[r] = mb; }
            }
            __syncthreads();
        }
    }
    for (int bb = tid; bb < NBKT; bb += 256) {
        int c = bcnt[bb];
        if (c > 0) {
            int gp = atomicAdd(&gcur[bb], c);
            for (int i = 0; i < c; ++i) pedges[gp + i] = buf[bb][i];
        }
    }
}

// ------------------------------------------------------------------ GEMM1: yz = x(bf16) . Wc^T
// 4 independent waves per block, 64 nodes each.
__global__ __launch_bounds__(256) void k_gemm1(const float* __restrict__ x,
                                               const unsigned short* __restrict__ Wc,
                                               unsigned short* __restrict__ yz) {
    const int wv = threadIdx.x >> 6;
    const int nb = blockIdx.x * 256 + wv * 64;
    if (nb >= N_NODES) return;
    const int lane = threadIdx.x & 63;
    const int lm = lane & 15, lk = lane >> 4;

    f32x4 acc[4][8];
#pragma unroll
    for (int a = 0; a < 4; ++a)
#pragma unroll
        for (int b = 0; b < 8; ++b) acc[a][b] = f32x4{0.f, 0.f, 0.f, 0.f};

#pragma unroll
    for (int kt = 0; kt < 4; ++kt) {
        const int ko = kt * 32 + lk * 8;
        bf8 af[4], bw[8];
#pragma unroll
        for (int mt = 0; mt < 4; ++mt) {
            int row = nb + mt * 16 + lm;
            if (row >= N_NODES) row = N_NODES - 1;
            const float* xp = x + (size_t)row * F_IN + ko;
            float4 v0 = *(const float4*)xp;
            float4 v1 = *(const float4*)(xp + 4);
            bf8 t;
            t[0] = (short)f2bf(v0.x); t[1] = (short)f2bf(v0.y);
            t[2] = (short)f2bf(v0.z); t[3] = (short)f2bf(v0.w);
            t[4] = (short)f2bf(v1.x); t[5] = (short)f2bf(v1.y);
            t[6] = (short)f2bf(v1.z); t[7] = (short)f2bf(v1.w);
            af[mt] = t;
        }
#pragma unroll
        for (int nt = 0; nt < 8; ++nt)
            bw[nt] = *reinterpret_cast<const bf8*>(Wc + (nt * 16 + lm) * 128 + ko);
#pragma unroll
        for (int mt = 0; mt < 4; ++mt)
#pragma unroll
            for (int nt = 0; nt < 8; ++nt)
                acc[mt][nt] = __builtin_amdgcn_mfma_f32_16x16x32_bf16(af[mt], bw[nt], acc[mt][nt], 0, 0, 0);
    }
#pragma unroll
    for (int mt = 0; mt < 4; ++mt)
#pragma unroll
        for (int r = 0; r < 4; ++r) {
            int node = nb + mt * 16 + lk * 4 + r;
            if (node < N_NODES) {
#pragma unroll
                for (int nt = 0; nt < 8; ++nt)
                    yz[(size_t)node * 128 + nt * 16 + lm] = f2bf(acc[nt == 0 ? mt : mt][nt][r]);
            }
        }
}

// ------------------------------------------------------------------ bucket agg in y-space + h-formation
// 512 threads (8 waves) per 128-node bucket. Pair-gather: lanes 0-31 take edge
// j, lanes 32-63 edge j+1; lane owns a dword (2 feats); combine via shfl_xor.
__global__ __launch_bounds__(512) void k_agg3(const unsigned short* __restrict__ yz,
                                              const unsigned* __restrict__ pedges,
                                              const int* __restrict__ bbase,
                                              const int* __restrict__ gbh,
                                              const float* __restrict__ bl,
                                              unsigned short* __restrict__ h) {
    __shared__ unsigned esrc[ECAP];          // 10.5 KB
    __shared__ int hcnt[128], hoff[128], hcur[128];
    const int tid = threadIdx.x, lane = tid & 63, wv = tid >> 6;
    const int bkt = blockIdx.x;
    int cnt = gbh[bkt]; if (cnt > ECAP) cnt = ECAP;
    const int base = bbase[bkt];
    if (tid < 128) hcnt[tid] = 0;
    __syncthreads();
    for (int i = tid; i < cnt; i += 512)
        atomicAdd(&hcnt[pedges[base + i] & 127], 1);
    __syncthreads();
    if (tid < 64) {
        int a = hcnt[2 * tid], b = hcnt[2 * tid + 1];
        int s = a + b;
#pragma unroll
        for (int d = 1; d < 64; d <<= 1) { int t = __shfl_up(s, d, 64); if (lane >= d) s += t; }
        int ex = s - (a + b);
        hoff[2 * tid] = ex;     hcur[2 * tid] = ex;
        hoff[2 * tid + 1] = ex + a; hcur[2 * tid + 1] = ex + a;
    }
    __syncthreads();
    for (int i = tid; i < cnt; i += 512) {
        unsigned e = pedges[base + i];
        int p = atomicAdd(&hcur[e & 127], 1);
        esrc[p] = e >> 7;
    }
    __syncthreads();
    const int p = lane >> 5;                 // which edge of the pair
    const int f2 = (lane & 31) * 2;          // feature pair owned by this lane
    float2 blv = *(const float2*)(bl + f2);
    for (int loc = wv; loc < 128; loc += 8) {
        int node = bkt * 128 + loc;
        if (node >= N_NODES) break;
        int st = hoff[loc], dg = hcnt[loc];
        float ax = 0.f, ay = 0.f;
        int j = 0;
        for (; j + 8 <= dg; j += 8) {
            unsigned e0 = esrc[st + j + 0 + p];
            unsigned e1 = esrc[st + j + 2 + p];
            unsigned e2 = esrc[st + j + 4 + p];
            unsigned e3 = esrc[st + j + 6 + p];
            unsigned u0 = *(const unsigned*)(yz + (size_t)e0 * 128 + f2);
            unsigned u1 = *(const unsigned*)(yz + (size_t)e1 * 128 + f2);
            unsigned u2 = *(const unsigned*)(yz + (size_t)e2 * 128 + f2);
            unsigned u3 = *(const unsigned*)(yz + (size_t)e3 * 128 + f2);
            ax += b2f(u0 & 0xffff) + b2f(u1 & 0xffff) + b2f(u2 & 0xffff) + b2f(u3 & 0xffff);
            ay += b2f(u0 >> 16) + b2f(u1 >> 16) + b2f(u2 >> 16) + b2f(u3 >> 16);
        }
        for (; j + 2 <= dg; j += 2) {
            unsigned e0 = esrc[st + j + p];
            unsigned u0 = *(const unsigned*)(yz + (size_t)e0 * 128 + f2);
            ax += b2f(u0 & 0xffff);
            ay += b2f(u0 >> 16);
        }
        if (j < dg && p == 0) {              // odd tail: first half only
            unsigned e0 = esrc[st + j];
            unsigned u0 = *(const unsigned*)(yz + (size_t)e0 * 128 + f2);
            ax += b2f(u0 & 0xffff);
            ay += b2f(u0 >> 16);
        }
        ax += __shfl_xor(ax, 32);
        ay += __shfl_xor(ay, 32);
        if (p == 0) {
            float inv = 1.0f / fmaxf((float)dg, 1.0f);
            unsigned zu = *(const unsigned*)(yz + (size_t)node * 128 + HID + f2);
            float vx = ax * inv + b2f(zu & 0xffff) + blv.x;
            float vy = ay * inv + b2f(zu >> 16) + blv.y;
            unsigned hv = (unsigned)f2bf(fmaxf(vx, 0.f)) | ((unsigned)f2bf(fmaxf(vy, 0.f)) << 16);
            *(unsigned*)(h + (size_t)node * HID + f2) = hv;
        }
    }
}

// ------------------------------------------------------------------ fused2: out = h.Wo^T + bout (proven r6)
__global__ __launch_bounds__(256, 2) void k_fused2(
    const unsigned short* __restrict__ h, const unsigned short* __restrict__ Wo,
    const float* __restrict__ bout, float* __restrict__ out) {

    __shared__ float sout[64 * OUT_F];       // 75 KB
    const int tid = threadIdx.x;
    const int lane = tid & 63;
    const int mt = tid >> 6;
    const int nb = blockIdx.x * 64;
    const int lm = lane & 15, lk = lane >> 4;

    int row = nb + mt * 16 + lm;
    if (row >= N_NODES) row = N_NODES - 1;
    bf8 ah[2];
#pragma unroll
    for (int k2 = 0; k2 < 2; ++k2)
        ah[k2] = *reinterpret_cast<const bf8*>(h + (size_t)row * HID + k2 * 32 + lk * 8);

    for (int g = 0; g < 5; ++g) {
        f32x4 acc2[4];
#pragma unroll
        for (int b = 0; b < 4; ++b) acc2[b] = f32x4{0.f, 0.f, 0.f, 0.f};
#pragma unroll
        for (int k2 = 0; k2 < 2; ++k2) {
            bf8 bw[4];
#pragma unroll
            for (int nt = 0; nt < 4; ++nt)
                bw[nt] = *reinterpret_cast<const bf8*>(
                    Wo + (size_t)((g * 4 + nt) * 16 + lm) * HID + k2 * 32 + lk * 8);
#pragma unroll
            for (int nt = 0; nt < 4; ++nt)
                acc2[nt] = __builtin_amdgcn_mfma_f32_16x16x32_bf16(ah[k2], bw[nt], acc2[nt], 0, 0, 0);
        }
#pragma unroll
        for (int nt = 0; nt < 4; ++nt) {
            int o = g * 64 + nt * 16 + lm;
            if (o < OUT_F) {
                float bo = bout[o];
#pragma unroll
                for (int r = 0; r < 4; ++r) {
                    int locn = mt * 16 + lk * 4 + r;
                    sout[locn * OUT_F + o] = acc2[nt][r] + bo;
                }
            }
        }
    }
    __syncthreads();
    const int nvalid = min(64, N_NODES - nb);
    const int total = nvalid * OUT_F;
    float* op = out + (size_t)nb * OUT_F;
    for (int i = tid; i < total; i += 256) op[i] = sout[i];
}

extern "C" void kernel_launch(void* const* d_in, const int* in_sizes, int n_in,
                              void* d_out, int out_size, void* d_ws, size_t ws_size,
                              hipStream_t stream) {
    const float* x    = (const float*)d_in[0];
    const int*   ei   = (const int*)d_in[1];
    const float* Wl   = (const float*)d_in[2];
    const float* bl   = (const float*)d_in[3];
    const float* Wr   = (const float*)d_in[4];
    const float* Wout = (const float*)d_in[5];
    const float* bout = (const float*)d_in[6];
    float* out = (float*)d_out;

    int nE = in_sizes[1] / 2;

    unsigned short* yz = (unsigned short*)d_ws;                   // 25.6 MB
    unsigned short* h  = yz + (size_t)N_NODES * 128;              // 12.8 MB
    unsigned* pedges = (unsigned*)(h + (size_t)N_NODES * HID);    // 6.48 MB
    int* gbh   = (int*)(pedges + 1620000);
    int* bbase = gbh + NBKT;
    int* gcur  = bbase + NBKT;
    unsigned short* Wc = (unsigned short*)(gcur + NBKT);          // 128*128
    unsigned short* Wo = Wc + 128 * 128;                          // 320*64

    int prep_n = 128 * 128 + WO_ROWS * HID + NBKT;
    k_prep<<<(prep_n + 255) / 256, 256, 0, stream>>>(Wl, Wr, Wout, Wc, Wo, gbh);
    k_bhist<<<512, 256, 0, stream>>>(ei, gbh, nE);
    k_bscan<<<1, 1024, 0, stream>>>(gbh, bbase, gcur);
    k_part<<<512, 256, 0, stream>>>(ei, gcur, pedges, nE);
    k_gemm1<<<(N_NODES + 255) / 256, 256, 0, stream>>>(x, Wc, yz);
    k_agg3<<<NBKT, 512, 0, stream>>>(yz, pedges, bbase, gbh, bl, h);
    k_fused2<<<(N_NODES + 63) / 64, 256, 0, stream>>>(h, Wo, bout, out);
}

// Round 8
// 154.349 us; speedup vs baseline: 9.8797x; 1.1961x over previous
//
#include <hip/hip_runtime.h>

#define N_NODES 100000
#define F_IN 128
#define HID 64
#define OUT_F 300
#define WO_ROWS 320         // 300 padded to 20 tiles of 16
#define NBKT 782            // ceil(100000 / 128) buckets of 128 nodes
#define BCAP 16             // partition staging slots per bucket (flush = 64B)
#define ECAP 2688           // fixed per-bucket segment (mean 2046, sigma 45 -> +14 sigma)
#define PART_BLOCKS 512
#define GEMM_BLOCKS 391     // ceil(100000 / 256)

typedef short bf8 __attribute__((ext_vector_type(8)));
typedef float f32x4 __attribute__((ext_vector_type(4)));

__device__ inline unsigned short f2bf(float f) {
    unsigned u = __builtin_bit_cast(unsigned, f);
    u += 0x7fff + ((u >> 16) & 1);          // round-to-nearest-even
    return (unsigned short)(u >> 16);
}
__device__ inline float b2f(unsigned short h) {
    return __builtin_bit_cast(float, (unsigned)h << 16);
}

// ------------------------------------------------------------------ prep: weights->bf16 + zero cursors
__global__ void k_prep(const float* __restrict__ Wl, const float* __restrict__ Wr,
                       const float* __restrict__ Wout,
                       unsigned short* __restrict__ Wc, unsigned short* __restrict__ Wo,
                       int* __restrict__ gcur) {
    int idx = blockIdx.x * blockDim.x + threadIdx.x;
    if (idx < 128 * 128) {
        int c = idx >> 7, k = idx & 127;
        float v = (c < HID) ? Wl[c * F_IN + k] : Wr[(c - HID) * F_IN + k];
        Wc[idx] = f2bf(v);
    } else if (idx < 128 * 128 + WO_ROWS * HID) {
        int j = idx - 128 * 128;
        int o = j >> 6, k = j & 63;
        Wo[j] = (o < OUT_F) ? f2bf(Wout[o * HID + k]) : (unsigned short)0;
    } else {
        int b = idx - 128 * 128 - WO_ROWS * HID;
        if (b < NBKT) gcur[b] = 0;
    }
}

// ------------------------------------------------------------------ merged partition + GEMM1
// Blocks [0,PART_BLOCKS): LDS-staged bucket partition of edges (proven r4-r7),
// writing into fixed-capacity per-bucket segments pedges[bkt*ECAP ...].
// Blocks [PART_BLOCKS, +GEMM_BLOCKS): yz = x(bf16) . Wc^T   (independent work,
// overlapped on the device instead of serialized on the stream).
__global__ __launch_bounds__(256) void k_pg(const int* __restrict__ ei,
                                            int* __restrict__ gcur,
                                            unsigned* __restrict__ pedges, int nE,
                                            const float* __restrict__ x,
                                            const unsigned short* __restrict__ Wc,
                                            unsigned short* __restrict__ yz) {
    if (blockIdx.x < PART_BLOCKS) {
        // ---------------- partition role ----------------
        __shared__ unsigned buf[NBKT][BCAP];     // 50 KB
        __shared__ int bcnt[NBKT];
        __shared__ unsigned rpk[256];
        __shared__ int rbk[256];
        __shared__ int rcnt;
        const int tid = threadIdx.x;
        for (int i = tid; i < NBKT; i += 256) bcnt[i] = 0;
        if (tid == 0) rcnt = 0;
        __syncthreads();
        const int per = (nE + PART_BLOCKS - 1) / PART_BLOCKS;
        const int e0 = blockIdx.x * per;
        const int e1 = min(e0 + per, nE);
        for (int base = e0; base < e1; base += 256) {
            const int e = base + tid;
            if (e < e1) {
                int src = ei[e];
                int dst = ei[nE + e];
                int b = dst >> 7;
                unsigned pk = ((unsigned)src << 7) | (unsigned)(dst & 127);
                int pos = atomicAdd(&bcnt[b], 1);
                if (pos < BCAP) buf[b][pos] = pk;
                else { int r = atomicAdd(&rcnt, 1); rpk[r] = pk; rbk[r] = b; }
            }
            __syncthreads();
            while (true) {
                for (int bb = tid; bb < NBKT; bb += 256) {
                    if (bcnt[bb] >= BCAP) {
                        int gp = atomicAdd(&gcur[bb], BCAP);
                        unsigned* dst = pedges + (size_t)bb * ECAP + gp;
#pragma unroll
                        for (int i = 0; i < BCAP; ++i) dst[i] = buf[bb][i];
                        bcnt[bb] = 0;
                    }
                }
                __syncthreads();
                int nr = rcnt;
                unsigned mpk = 0; int mb = -1;
                if (tid < nr) { mpk = rpk[tid]; mb = rbk[tid]; }
                __syncthreads();
                if (nr == 0) break;
                if (tid == 0) rcnt = 0;
                __syncthreads();
                if (mb >= 0) {
                    int pos = atomicAdd(&bcnt[mb], 1);
                    if (pos < BCAP) buf[mb][pos] = mpk;
                    else { int r = atomicAdd(&rcnt, 1); rpk[r] = mpk; rbk[r] = mb; }
                }
                __syncthreads();
            }
        }
        for (int bb = tid; bb < NBKT; bb += 256) {
            int c = bcnt[bb];
            if (c > 0) {
                int gp = atomicAdd(&gcur[bb], c);
                unsigned* dst = pedges + (size_t)bb * ECAP + gp;
                for (int i = 0; i < c; ++i) dst[i] = buf[bb][i];
            }
        }
    } else {
        // ---------------- GEMM1 role ----------------
        const int wv = threadIdx.x >> 6;
        const int nb = (blockIdx.x - PART_BLOCKS) * 256 + wv * 64;
        if (nb >= N_NODES) return;
        const int lane = threadIdx.x & 63;
        const int lm = lane & 15, lk = lane >> 4;

        f32x4 acc[4][8];
#pragma unroll
        for (int a = 0; a < 4; ++a)
#pragma unroll
            for (int b = 0; b < 8; ++b) acc[a][b] = f32x4{0.f, 0.f, 0.f, 0.f};

#pragma unroll
        for (int kt = 0; kt < 4; ++kt) {
            const int ko = kt * 32 + lk * 8;
            bf8 af[4], bw[8];
#pragma unroll
            for (int mt = 0; mt < 4; ++mt) {
                int row = nb + mt * 16 + lm;
                if (row >= N_NODES) row = N_NODES - 1;
                const float* xp = x + (size_t)row * F_IN + ko;
                float4 v0 = *(const float4*)xp;
                float4 v1 = *(const float4*)(xp + 4);
                bf8 t;
                t[0] = (short)f2bf(v0.x); t[1] = (short)f2bf(v0.y);
                t[2] = (short)f2bf(v0.z); t[3] = (short)f2bf(v0.w);
                t[4] = (short)f2bf(v1.x); t[5] = (short)f2bf(v1.y);
                t[6] = (short)f2bf(v1.z); t[7] = (short)f2bf(v1.w);
                af[mt] = t;
            }
#pragma unroll
            for (int nt = 0; nt < 8; ++nt)
                bw[nt] = *reinterpret_cast<const bf8*>(Wc + (nt * 16 + lm) * 128 + ko);
#pragma unroll
            for (int mt = 0; mt < 4; ++mt)
#pragma unroll
                for (int nt = 0; nt < 8; ++nt)
                    acc[mt][nt] = __builtin_amdgcn_mfma_f32_16x16x32_bf16(af[mt], bw[nt], acc[mt][nt], 0, 0, 0);
        }
#pragma unroll
        for (int mt = 0; mt < 4; ++mt)
#pragma unroll
            for (int r = 0; r < 4; ++r) {
                int node = nb + mt * 16 + lk * 4 + r;
                if (node < N_NODES) {
#pragma unroll
                    for (int nt = 0; nt < 8; ++nt)
                        yz[(size_t)node * 128 + nt * 16 + lm] = f2bf(acc[mt][nt][r]);
                }
            }
    }
}

// ------------------------------------------------------------------ bucket agg in y-space + h-formation
// 512 threads (8 waves) per 128-node bucket. Counting-sort edges in LDS, then
// 4-edge gather: lane owns 4 feats (dwordx2), q=lane>>4 picks edge of quad;
// two-stage shfl_xor(16,32) reduce; epilogue h = relu(mean + z + bl).
__global__ __launch_bounds__(512) void k_agg3(const unsigned short* __restrict__ yz,
                                              const unsigned* __restrict__ pedges,
                                              const int* __restrict__ gcur,
                                              const float* __restrict__ bl,
                                              unsigned short* __restrict__ h) {
    __shared__ unsigned esrc[ECAP];          // 10.5 KB
    __shared__ int hcnt[128], hoff[128], hcur[128];
    const int tid = threadIdx.x, lane = tid & 63, wv = tid >> 6;
    const int bkt = blockIdx.x;
    int cnt = gcur[bkt]; if (cnt > ECAP) cnt = ECAP;
    const size_t base = (size_t)bkt * ECAP;
    if (tid < 128) hcnt[tid] = 0;
    __syncthreads();
    for (int i = tid; i < cnt; i += 512)
        atomicAdd(&hcnt[pedges[base + i] & 127], 1);
    __syncthreads();
    if (tid < 64) {
        int a = hcnt[2 * tid], b = hcnt[2 * tid + 1];
        int s = a + b;
#pragma unroll
        for (int d = 1; d < 64; d <<= 1) { int t = __shfl_up(s, d, 64); if (lane >= d) s += t; }
        int ex = s - (a + b);
        hoff[2 * tid] = ex;     hcur[2 * tid] = ex;
        hoff[2 * tid + 1] = ex + a; hcur[2 * tid + 1] = ex + a;
    }
    __syncthreads();
    for (int i = tid; i < cnt; i += 512) {
        unsigned e = pedges[base + i];
        int p = atomicAdd(&hcur[e & 127], 1);
        esrc[p] = e >> 7;
    }
    __syncthreads();
    const int q = lane >> 4;                 // edge slot of the quad
    const int f4 = (lane & 15) * 4;          // 4 features owned by this lane
    float4 blv = *(const float4*)(bl + f4);
    for (int loc = wv; loc < 128; loc += 8) {
        int node = bkt * 128 + loc;
        if (node >= N_NODES) break;
        int st = hoff[loc], dg = hcnt[loc];
        float s0 = 0.f, s1 = 0.f, s2 = 0.f, s3 = 0.f;
        int j = 0;
        for (; j + 8 <= dg; j += 8) {
            unsigned eA = esrc[st + j + q];
            unsigned eB = esrc[st + j + 4 + q];
            uint2 uA = *(const uint2*)(yz + (size_t)eA * 128 + f4);
            uint2 uB = *(const uint2*)(yz + (size_t)eB * 128 + f4);
            s0 += b2f(uA.x & 0xffff) + b2f(uB.x & 0xffff);
            s1 += b2f(uA.x >> 16)    + b2f(uB.x >> 16);
            s2 += b2f(uA.y & 0xffff) + b2f(uB.y & 0xffff);
            s3 += b2f(uA.y >> 16)    + b2f(uB.y >> 16);
        }
        if (j + 4 <= dg) {
            unsigned eA = esrc[st + j + q];
            uint2 uA = *(const uint2*)(yz + (size_t)eA * 128 + f4);
            s0 += b2f(uA.x & 0xffff);
            s1 += b2f(uA.x >> 16);
            s2 += b2f(uA.y & 0xffff);
            s3 += b2f(uA.y >> 16);
            j += 4;
        }
        int rem = dg - j;
        if (q < rem) {                        // tail 0..3 edges, one per quad slot
            unsigned eA = esrc[st + j + q];
            uint2 uA = *(const uint2*)(yz + (size_t)eA * 128 + f4);
            s0 += b2f(uA.x & 0xffff);
            s1 += b2f(uA.x >> 16);
            s2 += b2f(uA.y & 0xffff);
            s3 += b2f(uA.y >> 16);
        }
        s0 += __shfl_xor(s0, 16); s0 += __shfl_xor(s0, 32);
        s1 += __shfl_xor(s1, 16); s1 += __shfl_xor(s1, 32);
        s2 += __shfl_xor(s2, 16); s2 += __shfl_xor(s2, 32);
        s3 += __shfl_xor(s3, 16); s3 += __shfl_xor(s3, 32);
        if (q == 0) {
            float inv = 1.0f / fmaxf((float)dg, 1.0f);
            uint2 zu = *(const uint2*)(yz + (size_t)node * 128 + HID + f4);
            float v0 = s0 * inv + b2f(zu.x & 0xffff) + blv.x;
            float v1 = s1 * inv + b2f(zu.x >> 16)    + blv.y;
            float v2 = s2 * inv + b2f(zu.y & 0xffff) + blv.z;
            float v3 = s3 * inv + b2f(zu.y >> 16)    + blv.w;
            uint2 hv;
            hv.x = (unsigned)f2bf(fmaxf(v0, 0.f)) | ((unsigned)f2bf(fmaxf(v1, 0.f)) << 16);
            hv.y = (unsigned)f2bf(fmaxf(v2, 0.f)) | ((unsigned)f2bf(fmaxf(v3, 0.f)) << 16);
            *(uint2*)(h + (size_t)node * HID + f4) = hv;
        }
    }
}

// ------------------------------------------------------------------ fused2: out = h.Wo^T + bout (proven r6/r7)
__global__ __launch_bounds__(256, 2) void k_fused2(
    const unsigned short* __restrict__ h, const unsigned short* __restrict__ Wo,
    const float* __restrict__ bout, float* __restrict__ out) {

    __shared__ float sout[64 * OUT_F];       // 75 KB
    const int tid = threadIdx.x;
    const int lane = tid & 63;
    const int mt = tid >> 6;
    const int nb = blockIdx.x * 64;
    const int lm = lane & 15, lk = lane >> 4;

    int row = nb + mt * 16 + lm;
    if (row >= N_NODES) row = N_NODES - 1;
    bf8 ah[2];
#pragma unroll
    for (int k2 = 0; k2 < 2; ++k2)
        ah[k2] = *reinterpret_cast<const bf8*>(h + (size_t)row * HID + k2 * 32 + lk * 8);

    for (int g = 0; g < 5; ++g) {
        f32x4 acc2[4];
#pragma unroll
        for (int b = 0; b < 4; ++b) acc2[b] = f32x4{0.f, 0.f, 0.f, 0.f};
#pragma unroll
        for (int k2 = 0; k2 < 2; ++k2) {
            bf8 bw[4];
#pragma unroll
            for (int nt = 0; nt < 4; ++nt)
                bw[nt] = *reinterpret_cast<const bf8*>(
                    Wo + (size_t)((g * 4 + nt) * 16 + lm) * HID + k2 * 32 + lk * 8);
#pragma unroll
            for (int nt = 0; nt < 4; ++nt)
                acc2[nt] = __builtin_amdgcn_mfma_f32_16x16x32_bf16(ah[k2], bw[nt], acc2[nt], 0, 0, 0);
        }
#pragma unroll
        for (int nt = 0; nt < 4; ++nt) {
            int o = g * 64 + nt * 16 + lm;
            if (o < OUT_F) {
                float bo = bout[o];
#pragma unroll
                for (int r = 0; r < 4; ++r) {
                    int locn = mt * 16 + lk * 4 + r;
                    sout[locn * OUT_F + o] = acc2[nt][r] + bo;
                }
            }
        }
    }
    __syncthreads();
    const int nvalid = min(64, N_NODES - nb);
    const int total = nvalid * OUT_F;
    float* op = out + (size_t)nb * OUT_F;
    for (int i = tid; i < total; i += 256) op[i] = sout[i];
}

extern "C" void kernel_launch(void* const* d_in, const int* in_sizes, int n_in,
                              void* d_out, int out_size, void* d_ws, size_t ws_size,
                              hipStream_t stream) {
    const float* x    = (const float*)d_in[0];
    const int*   ei   = (const int*)d_in[1];
    const float* Wl   = (const float*)d_in[2];
    const float* bl   = (const float*)d_in[3];
    const float* Wr   = (const float*)d_in[4];
    const float* Wout = (const float*)d_in[5];
    const float* bout = (const float*)d_in[6];
    float* out = (float*)d_out;

    int nE = in_sizes[1] / 2;

    unsigned short* yz = (unsigned short*)d_ws;                   // 25.6 MB
    unsigned short* h  = yz + (size_t)N_NODES * 128;              // 12.8 MB
    unsigned* pedges = (unsigned*)(h + (size_t)N_NODES * HID);    // 8.41 MB (NBKT*ECAP)
    int* gcur  = (int*)(pedges + (size_t)NBKT * ECAP);
    unsigned short* Wc = (unsigned short*)(gcur + NBKT);          // 128*128
    unsigned short* Wo = Wc + 128 * 128;                          // 320*64

    int prep_n = 128 * 128 + WO_ROWS * HID + NBKT;
    k_prep<<<(prep_n + 255) / 256, 256, 0, stream>>>(Wl, Wr, Wout, Wc, Wo, gcur);
    k_pg<<<PART_BLOCKS + GEMM_BLOCKS, 256, 0, stream>>>(ei, gcur, pedges, nE, x, Wc, yz);
    k_agg3<<<NBKT, 512, 0, stream>>>(yz, pedges, gcur, bl, h);
    k_fused2<<<(N_NODES + 63) / 64, 256, 0, stream>>>(h, Wo, bout, out);
}

// Round 9
// 142.000 us; speedup vs baseline: 10.7389x; 1.0870x over previous
//
#include <hip/hip_runtime.h>

#define N_NODES 100000
#define F_IN 128
#define HID 64
#define OUT_F 300
#define WO_ROWS 320         // 300 padded to 20 tiles of 16
#define NBKT 782            // ceil(100000 / 128) buckets of 128 nodes
#define ECAP 2688           // fixed per-bucket segment (mean 2046, sigma 45 -> +14 sigma)
#define PART_BLOCKS 256
#define GEMM_BLOCKS 391     // ceil(100000 / 256)
#define SORT_CAP 6400       // per-chunk LDS sort capacity (>= ceil(1.6M/256))

typedef short bf8 __attribute__((ext_vector_type(8)));
typedef float f32x4 __attribute__((ext_vector_type(4)));

__device__ inline unsigned short f2bf(float f) {
    unsigned u = __builtin_bit_cast(unsigned, f);
    u += 0x7fff + ((u >> 16) & 1);          // round-to-nearest-even
    return (unsigned short)(u >> 16);
}
__device__ inline float b2f(unsigned short h) {
    return __builtin_bit_cast(float, (unsigned)h << 16);
}

// ------------------------------------------------------------------ prep: weights->bf16 + zero cursors
__global__ void k_prep(const float* __restrict__ Wl, const float* __restrict__ Wr,
                       const float* __restrict__ Wout,
                       unsigned short* __restrict__ Wc, unsigned short* __restrict__ Wo,
                       int* __restrict__ gcur) {
    int idx = blockIdx.x * blockDim.x + threadIdx.x;
    if (idx < 128 * 128) {
        int c = idx >> 7, k = idx & 127;
        float v = (c < HID) ? Wl[c * F_IN + k] : Wr[(c - HID) * F_IN + k];
        Wc[idx] = f2bf(v);
    } else if (idx < 128 * 128 + WO_ROWS * HID) {
        int j = idx - 128 * 128;
        int o = j >> 6, k = j & 63;
        Wo[j] = (o < OUT_F) ? f2bf(Wout[o * HID + k]) : (unsigned short)0;
    } else {
        int b = idx - 128 * 128 - WO_ROWS * HID;
        if (b < NBKT) gcur[b] = 0;
    }
}

// ------------------------------------------------------------------ merged partition + GEMM1
// Blocks [0,PART_BLOCKS): counting-sort partition — per-block LDS sort of its
// edge range by bucket, then contiguous run writes at atomic cursors.
// Blocks [PART_BLOCKS, +GEMM_BLOCKS): yz = x(bf16) . Wc^T (overlapped).
__global__ __launch_bounds__(256) void k_pg(const int* __restrict__ ei,
                                            int* __restrict__ gcur,
                                            unsigned* __restrict__ pedges, int nE,
                                            const float* __restrict__ x,
                                            const unsigned short* __restrict__ Wc,
                                            unsigned short* __restrict__ yz) {
    if (blockIdx.x < PART_BLOCKS) {
        // ---------------- counting-sort partition role ----------------
        __shared__ unsigned sorted[SORT_CAP];    // 25.6 KB
        __shared__ int hcnt[1024], hoff[1024], hcur[1024];   // 12 KB (782 used)
        __shared__ int wpre[8];
        const int tid = threadIdx.x, lane = tid & 63, wid = tid >> 6;
        const int per = (nE + PART_BLOCKS - 1) / PART_BLOCKS;
        const int e0 = blockIdx.x * per;
        const int e1 = min(e0 + per, nE);
        for (int cb = e0; cb < e1; cb += SORT_CAP) {
            const int cnt = min(SORT_CAP, e1 - cb);
            // zero hist
#pragma unroll
            for (int i = 0; i < 4; ++i) hcnt[tid * 4 + i] = 0;
            __syncthreads();
            // pass 1: histogram of dst buckets (coalesced read)
            for (int i = tid; i < cnt; i += 256)
                atomicAdd(&hcnt[ei[nE + cb + i] >> 7], 1);
            __syncthreads();
            // block scan of 1024 bins, 4 per thread
            int c0 = hcnt[tid * 4], c1 = hcnt[tid * 4 + 1];
            int c2 = hcnt[tid * 4 + 2], c3 = hcnt[tid * 4 + 3];
            int tsum = c0 + c1 + c2 + c3;
            int s = tsum;
#pragma unroll
            for (int d = 1; d < 64; d <<= 1) { int t = __shfl_up(s, d, 64); if (lane >= d) s += t; }
            if (lane == 63) wpre[wid] = s;       // wave totals
            __syncthreads();
            if (tid == 0) { int run = 0; for (int w = 0; w < 4; ++w) { int t = wpre[w]; wpre[w] = run; run += t; } }
            __syncthreads();
            int excl = wpre[wid] + (s - tsum);
            hoff[tid * 4 + 0] = excl;                 hcur[tid * 4 + 0] = excl;
            hoff[tid * 4 + 1] = excl + c0;            hcur[tid * 4 + 1] = excl + c0;
            hoff[tid * 4 + 2] = excl + c0 + c1;       hcur[tid * 4 + 2] = excl + c0 + c1;
            hoff[tid * 4 + 3] = excl + c0 + c1 + c2;  hcur[tid * 4 + 3] = excl + c0 + c1 + c2;
            __syncthreads();
            // pass 2: scatter packed edges into sorted order (L2-hot reread)
            for (int i = tid; i < cnt; i += 256) {
                int src = ei[cb + i];
                int dst = ei[nE + cb + i];
                unsigned pk = ((unsigned)src << 7) | (unsigned)(dst & 127);
                int p = atomicAdd(&hcur[dst >> 7], 1);
                sorted[p] = pk;
            }
            __syncthreads();
            // write out: one contiguous run per non-empty bucket
            for (int b = tid; b < NBKT; b += 256) {
                int c = hcnt[b];
                if (c > 0) {
                    int gp = atomicAdd(&gcur[b], c);
                    unsigned* dst = pedges + (size_t)b * ECAP + gp;
                    int off = hoff[b];
                    for (int i = 0; i < c; ++i) dst[i] = sorted[off + i];
                }
            }
            __syncthreads();
        }
    } else {
        // ---------------- GEMM1 role (proven r7/r8) ----------------
        const int wv = threadIdx.x >> 6;
        const int nb = (blockIdx.x - PART_BLOCKS) * 256 + wv * 64;
        if (nb >= N_NODES) return;
        const int lane = threadIdx.x & 63;
        const int lm = lane & 15, lk = lane >> 4;

        f32x4 acc[4][8];
#pragma unroll
        for (int a = 0; a < 4; ++a)
#pragma unroll
            for (int b = 0; b < 8; ++b) acc[a][b] = f32x4{0.f, 0.f, 0.f, 0.f};

#pragma unroll
        for (int kt = 0; kt < 4; ++kt) {
            const int ko = kt * 32 + lk * 8;
            bf8 af[4], bw[8];
#pragma unroll
            for (int mt = 0; mt < 4; ++mt) {
                int row = nb + mt * 16 + lm;
                if (row >= N_NODES) row = N_NODES - 1;
                const float* xp = x + (size_t)row * F_IN + ko;
                float4 v0 = *(const float4*)xp;
                float4 v1 = *(const float4*)(xp + 4);
                bf8 t;
                t[0] = (short)f2bf(v0.x); t[1] = (short)f2bf(v0.y);
                t[2] = (short)f2bf(v0.z); t[3] = (short)f2bf(v0.w);
                t[4] = (short)f2bf(v1.x); t[5] = (short)f2bf(v1.y);
                t[6] = (short)f2bf(v1.z); t[7] = (short)f2bf(v1.w);
                af[mt] = t;
            }
#pragma unroll
            for (int nt = 0; nt < 8; ++nt)
                bw[nt] = *reinterpret_cast<const bf8*>(Wc + (nt * 16 + lm) * 128 + ko);
#pragma unroll
            for (int mt = 0; mt < 4; ++mt)
#pragma unroll
                for (int nt = 0; nt < 8; ++nt)
                    acc[mt][nt] = __builtin_amdgcn_mfma_f32_16x16x32_bf16(af[mt], bw[nt], acc[mt][nt], 0, 0, 0);
        }
#pragma unroll
        for (int mt = 0; mt < 4; ++mt)
#pragma unroll
            for (int r = 0; r < 4; ++r) {
                int node = nb + mt * 16 + lk * 4 + r;
                if (node < N_NODES) {
#pragma unroll
                    for (int nt = 0; nt < 8; ++nt)
                        yz[(size_t)node * 128 + nt * 16 + lm] = f2bf(acc[mt][nt][r]);
                }
            }
    }
}

// ------------------------------------------------------------------ bucket agg in y-space + h-formation (proven r8)
__global__ __launch_bounds__(512) void k_agg3(const unsigned short* __restrict__ yz,
                                              const unsigned* __restrict__ pedges,
                                              const int* __restrict__ gcur,
                                              const float* __restrict__ bl,
                                              unsigned short* __restrict__ h) {
    __shared__ unsigned esrc[ECAP];          // 10.5 KB
    __shared__ int hcnt[128], hoff[128], hcur[128];
    const int tid = threadIdx.x, lane = tid & 63, wv = tid >> 6;
    const int bkt = blockIdx.x;
    int cnt = gcur[bkt]; if (cnt > ECAP) cnt = ECAP;
    const size_t base = (size_t)bkt * ECAP;
    if (tid < 128) hcnt[tid] = 0;
    __syncthreads();
    for (int i = tid; i < cnt; i += 512)
        atomicAdd(&hcnt[pedges[base + i] & 127], 1);
    __syncthreads();
    if (tid < 64) {
        int a = hcnt[2 * tid], b = hcnt[2 * tid + 1];
        int s = a + b;
#pragma unroll
        for (int d = 1; d < 64; d <<= 1) { int t = __shfl_up(s, d, 64); if (lane >= d) s += t; }
        int ex = s - (a + b);
        hoff[2 * tid] = ex;     hcur[2 * tid] = ex;
        hoff[2 * tid + 1] = ex + a; hcur[2 * tid + 1] = ex + a;
    }
    __syncthreads();
    for (int i = tid; i < cnt; i += 512) {
        unsigned e = pedges[base + i];
        int p = atomicAdd(&hcur[e & 127], 1);
        esrc[p] = e >> 7;
    }
    __syncthreads();
    const int q = lane >> 4;                 // edge slot of the quad
    const int f4 = (lane & 15) * 4;          // 4 features owned by this lane
    float4 blv = *(const float4*)(bl + f4);
    for (int loc = wv; loc < 128; loc += 8) {
        int node = bkt * 128 + loc;
        if (node >= N_NODES) break;
        int st = hoff[loc], dg = hcnt[loc];
        float s0 = 0.f, s1 = 0.f, s2 = 0.f, s3 = 0.f;
        int j = 0;
        for (; j + 8 <= dg; j += 8) {
            unsigned eA = esrc[st + j + q];
            unsigned eB = esrc[st + j + 4 + q];
            uint2 uA = *(const uint2*)(yz + (size_t)eA * 128 + f4);
            uint2 uB = *(const uint2*)(yz + (size_t)eB * 128 + f4);
            s0 += b2f(uA.x & 0xffff) + b2f(uB.x & 0xffff);
            s1 += b2f(uA.x >> 16)    + b2f(uB.x >> 16);
            s2 += b2f(uA.y & 0xffff) + b2f(uB.y & 0xffff);
            s3 += b2f(uA.y >> 16)    + b2f(uB.y >> 16);
        }
        if (j + 4 <= dg) {
            unsigned eA = esrc[st + j + q];
            uint2 uA = *(const uint2*)(yz + (size_t)eA * 128 + f4);
            s0 += b2f(uA.x & 0xffff);
            s1 += b2f(uA.x >> 16);
            s2 += b2f(uA.y & 0xffff);
            s3 += b2f(uA.y >> 16);
            j += 4;
        }
        int rem = dg - j;
        if (q < rem) {
            unsigned eA = esrc[st + j + q];
            uint2 uA = *(const uint2*)(yz + (size_t)eA * 128 + f4);
            s0 += b2f(uA.x & 0xffff);
            s1 += b2f(uA.x >> 16);
            s2 += b2f(uA.y & 0xffff);
            s3 += b2f(uA.y >> 16);
        }
        s0 += __shfl_xor(s0, 16); s0 += __shfl_xor(s0, 32);
        s1 += __shfl_xor(s1, 16); s1 += __shfl_xor(s1, 32);
        s2 += __shfl_xor(s2, 16); s2 += __shfl_xor(s2, 32);
        s3 += __shfl_xor(s3, 16); s3 += __shfl_xor(s3, 32);
        if (q == 0) {
            float inv = 1.0f / fmaxf((float)dg, 1.0f);
            uint2 zu = *(const uint2*)(yz + (size_t)node * 128 + HID + f4);
            float v0 = s0 * inv + b2f(zu.x & 0xffff) + blv.x;
            float v1 = s1 * inv + b2f(zu.x >> 16)    + blv.y;
            float v2 = s2 * inv + b2f(zu.y & 0xffff) + blv.z;
            float v3 = s3 * inv + b2f(zu.y >> 16)    + blv.w;
            uint2 hv;
            hv.x = (unsigned)f2bf(fmaxf(v0, 0.f)) | ((unsigned)f2bf(fmaxf(v1, 0.f)) << 16);
            hv.y = (unsigned)f2bf(fmaxf(v2, 0.f)) | ((unsigned)f2bf(fmaxf(v3, 0.f)) << 16);
            *(uint2*)(h + (size_t)node * HID + f4) = hv;
        }
    }
}

// ------------------------------------------------------------------ fused2: out = h.Wo^T + bout (proven r6-r8)
__global__ __launch_bounds__(256, 2) void k_fused2(
    const unsigned short* __restrict__ h, const unsigned short* __restrict__ Wo,
    const float* __restrict__ bout, float* __restrict__ out) {

    __shared__ float sout[64 * OUT_F];       // 75 KB
    const int tid = threadIdx.x;
    const int lane = tid & 63;
    const int mt = tid >> 6;
    const int nb = blockIdx.x * 64;
    const int lm = lane & 15, lk = lane >> 4;

    int row = nb + mt * 16 + lm;
    if (row >= N_NODES) row = N_NODES - 1;
    bf8 ah[2];
#pragma unroll
    for (int k2 = 0; k2 < 2; ++k2)
        ah[k2] = *reinterpret_cast<const bf8*>(h + (size_t)row * HID + k2 * 32 + lk * 8);

    for (int g = 0; g < 5; ++g) {
        f32x4 acc2[4];
#pragma unroll
        for (int b = 0; b < 4; ++b) acc2[b] = f32x4{0.f, 0.f, 0.f, 0.f};
#pragma unroll
        for (int k2 = 0; k2 < 2; ++k2) {
            bf8 bw[4];
#pragma unroll
            for (int nt = 0; nt < 4; ++nt)
                bw[nt] = *reinterpret_cast<const bf8*>(
                    Wo + (size_t)((g * 4 + nt) * 16 + lm) * HID + k2 * 32 + lk * 8);
#pragma unroll
            for (int nt = 0; nt < 4; ++nt)
                acc2[nt] = __builtin_amdgcn_mfma_f32_16x16x32_bf16(ah[k2], bw[nt], acc2[nt], 0, 0, 0);
        }
#pragma unroll
        for (int nt = 0; nt < 4; ++nt) {
            int o = g * 64 + nt * 16 + lm;
            if (o < OUT_F) {
                float bo = bout[o];
#pragma unroll
                for (int r = 0; r < 4; ++r) {
                    int locn = mt * 16 + lk * 4 + r;
                    sout[locn * OUT_F + o] = acc2[nt][r] + bo;
                }
            }
        }
    }
    __syncthreads();
    const int nvalid = min(64, N_NODES - nb);
    const int total = nvalid * OUT_F;
    float* op = out + (size_t)nb * OUT_F;
    for (int i = tid; i < total; i += 256) op[i] = sout[i];
}

extern "C" void kernel_launch(void* const* d_in, const int* in_sizes, int n_in,
                              void* d_out, int out_size, void* d_ws, size_t ws_size,
                              hipStream_t stream) {
    const float* x    = (const float*)d_in[0];
    const int*   ei   = (const int*)d_in[1];
    const float* Wl   = (const float*)d_in[2];
    const float* bl   = (const float*)d_in[3];
    const float* Wr   = (const float*)d_in[4];
    const float* Wout = (const float*)d_in[5];
    const float* bout = (const float*)d_in[6];
    float* out = (float*)d_out;

    int nE = in_sizes[1] / 2;

    unsigned short* yz = (unsigned short*)d_ws;                   // 25.6 MB
    unsigned short* h  = yz + (size_t)N_NODES * 128;              // 12.8 MB
    unsigned* pedges = (unsigned*)(h + (size_t)N_NODES * HID);    // 8.41 MB (NBKT*ECAP)
    int* gcur  = (int*)(pedges + (size_t)NBKT * ECAP);
    unsigned short* Wc = (unsigned short*)(gcur + NBKT);          // 128*128
    unsigned short* Wo = Wc + 128 * 128;                          // 320*64

    int prep_n = 128 * 128 + WO_ROWS * HID + NBKT;
    k_prep<<<(prep_n + 255) / 256, 256, 0, stream>>>(Wl, Wr, Wout, Wc, Wo, gcur);
    k_pg<<<PART_BLOCKS + GEMM_BLOCKS, 256, 0, stream>>>(ei, gcur, pedges, nE, x, Wc, yz);
    k_agg3<<<NBKT, 512, 0, stream>>>(yz, pedges, gcur, bl, h);
    k_fused2<<<(N_NODES + 63) / 64, 256, 0, stream>>>(h, Wo, bout, out);
}

// Round 10
// 134.681 us; speedup vs baseline: 11.3225x; 1.0543x over previous
//
#include <hip/hip_runtime.h>

#define N_NODES 100000
#define F_IN 128
#define HID 64
#define OUT_F 300
#define WO_ROWS 320         // 300 padded to 20 tiles of 16
#define NBKT 782            // ceil(100000 / 128) buckets of 128 nodes
#define ECAP 2688           // fixed per-bucket segment (mean 2046, sigma 45 -> +14 sigma)
#define PART_BLOCKS 256
#define GEMM_BLOCKS 196     // ceil(100000 / 512)
#define SORT_CAP 6400       // per-chunk LDS sort capacity (>= ceil(1.6M/256))

typedef short bf8 __attribute__((ext_vector_type(8)));
typedef float f32x4 __attribute__((ext_vector_type(4)));

__device__ inline unsigned short f2bf(float f) {
    unsigned u = __builtin_bit_cast(unsigned, f);
    u += 0x7fff + ((u >> 16) & 1);          // round-to-nearest-even
    return (unsigned short)(u >> 16);
}
__device__ inline float b2f(unsigned short h) {
    return __builtin_bit_cast(float, (unsigned)h << 16);
}

// ------------------------------------------------------------------ prep: weights->bf16 + zero cursors
__global__ void k_prep(const float* __restrict__ Wl, const float* __restrict__ Wr,
                       const float* __restrict__ Wout,
                       unsigned short* __restrict__ Wc, unsigned short* __restrict__ Wo,
                       int* __restrict__ gcur) {
    int idx = blockIdx.x * blockDim.x + threadIdx.x;
    if (idx < 128 * 128) {
        int c = idx >> 7, k = idx & 127;
        float v = (c < HID) ? Wl[c * F_IN + k] : Wr[(c - HID) * F_IN + k];
        Wc[idx] = f2bf(v);
    } else if (idx < 128 * 128 + WO_ROWS * HID) {
        int j = idx - 128 * 128;
        int o = j >> 6, k = j & 63;
        Wo[j] = (o < OUT_F) ? f2bf(Wout[o * HID + k]) : (unsigned short)0;
    } else {
        int b = idx - 128 * 128 - WO_ROWS * HID;
        if (b < NBKT) gcur[b] = 0;
    }
}

// ------------------------------------------------------------------ merged partition + GEMM1, 512 threads
// Blocks [0,PART_BLOCKS): counting-sort partition (8 waves -> 2x latency hiding).
// Blocks [PART_BLOCKS, +GEMM_BLOCKS): yz = x(bf16).Wc^T, 8 waves x 64 nodes.
__global__ __launch_bounds__(512) void k_pg(const int* __restrict__ ei,
                                            int* __restrict__ gcur,
                                            unsigned* __restrict__ pedges, int nE,
                                            const float* __restrict__ x,
                                            const unsigned short* __restrict__ Wc,
                                            unsigned short* __restrict__ yz) {
    if (blockIdx.x < PART_BLOCKS) {
        // ---------------- counting-sort partition role ----------------
        __shared__ unsigned sorted[SORT_CAP];    // 25.6 KB
        __shared__ int hcnt[1024], hoff[1024], hcur[1024];   // 12 KB (782 used)
        __shared__ int wpre[8];
        const int tid = threadIdx.x, lane = tid & 63, wid = tid >> 6;
        const int per = (nE + PART_BLOCKS - 1) / PART_BLOCKS;
        const int e0 = blockIdx.x * per;
        const int e1 = min(e0 + per, nE);
        for (int cb = e0; cb < e1; cb += SORT_CAP) {
            const int cnt = min(SORT_CAP, e1 - cb);
            // zero hist (2 bins/thread)
            hcnt[tid * 2] = 0; hcnt[tid * 2 + 1] = 0;
            __syncthreads();
            // pass 1: histogram of dst buckets (coalesced read)
            for (int i = tid; i < cnt; i += 512)
                atomicAdd(&hcnt[ei[nE + cb + i] >> 7], 1);
            __syncthreads();
            // block scan of 1024 bins, 2 per thread
            int c0 = hcnt[tid * 2], c1 = hcnt[tid * 2 + 1];
            int tsum = c0 + c1;
            int s = tsum;
#pragma unroll
            for (int d = 1; d < 64; d <<= 1) { int t = __shfl_up(s, d, 64); if (lane >= d) s += t; }
            if (lane == 63) wpre[wid] = s;       // wave totals
            __syncthreads();
            if (tid == 0) { int run = 0; for (int w = 0; w < 8; ++w) { int t = wpre[w]; wpre[w] = run; run += t; } }
            __syncthreads();
            int excl = wpre[wid] + (s - tsum);
            hoff[tid * 2 + 0] = excl;       hcur[tid * 2 + 0] = excl;
            hoff[tid * 2 + 1] = excl + c0;  hcur[tid * 2 + 1] = excl + c0;
            __syncthreads();
            // pass 2: scatter packed edges into sorted order (L2-hot reread)
            for (int i = tid; i < cnt; i += 512) {
                int src = ei[cb + i];
                int dst = ei[nE + cb + i];
                unsigned pk = ((unsigned)src << 7) | (unsigned)(dst & 127);
                int p = atomicAdd(&hcur[dst >> 7], 1);
                sorted[p] = pk;
            }
            __syncthreads();
            // write out: one contiguous run per non-empty bucket
            for (int b = tid; b < NBKT; b += 512) {
                int c = hcnt[b];
                if (c > 0) {
                    int gp = atomicAdd(&gcur[b], c);
                    unsigned* dst = pedges + (size_t)b * ECAP + gp;
                    int off = hoff[b];
                    for (int i = 0; i < c; ++i) dst[i] = sorted[off + i];
                }
            }
            __syncthreads();
        }
    } else {
        // ---------------- GEMM1 role (proven r7-r9), 8 waves ----------------
        const int wv = threadIdx.x >> 6;
        const int nb = (blockIdx.x - PART_BLOCKS) * 512 + wv * 64;
        if (nb >= N_NODES) return;
        const int lane = threadIdx.x & 63;
        const int lm = lane & 15, lk = lane >> 4;

        f32x4 acc[4][8];
#pragma unroll
        for (int a = 0; a < 4; ++a)
#pragma unroll
            for (int b = 0; b < 8; ++b) acc[a][b] = f32x4{0.f, 0.f, 0.f, 0.f};

#pragma unroll
        for (int kt = 0; kt < 4; ++kt) {
            const int ko = kt * 32 + lk * 8;
            bf8 af[4], bw[8];
#pragma unroll
            for (int mt = 0; mt < 4; ++mt) {
                int row = nb + mt * 16 + lm;
                if (row >= N_NODES) row = N_NODES - 1;
                const float* xp = x + (size_t)row * F_IN + ko;
                float4 v0 = *(const float4*)xp;
                float4 v1 = *(const float4*)(xp + 4);
                bf8 t;
                t[0] = (short)f2bf(v0.x); t[1] = (short)f2bf(v0.y);
                t[2] = (short)f2bf(v0.z); t[3] = (short)f2bf(v0.w);
                t[4] = (short)f2bf(v1.x); t[5] = (short)f2bf(v1.y);
                t[6] = (short)f2bf(v1.z); t[7] = (short)f2bf(v1.w);
                af[mt] = t;
            }
#pragma unroll
            for (int nt = 0; nt < 8; ++nt)
                bw[nt] = *reinterpret_cast<const bf8*>(Wc + (nt * 16 + lm) * 128 + ko);
#pragma unroll
            for (int mt = 0; mt < 4; ++mt)
#pragma unroll
                for (int nt = 0; nt < 8; ++nt)
                    acc[mt][nt] = __builtin_amdgcn_mfma_f32_16x16x32_bf16(af[mt], bw[nt], acc[mt][nt], 0, 0, 0);
        }
#pragma unroll
        for (int mt = 0; mt < 4; ++mt)
#pragma unroll
            for (int r = 0; r < 4; ++r) {
                int node = nb + mt * 16 + lk * 4 + r;
                if (node < N_NODES) {
#pragma unroll
                    for (int nt = 0; nt < 8; ++nt)
                        yz[(size_t)node * 128 + nt * 16 + lm] = f2bf(acc[mt][nt][r]);
                }
            }
    }
}

// ------------------------------------------------------------------ bucket agg in y-space + h-formation (proven r8/r9)
__global__ __launch_bounds__(512) void k_agg3(const unsigned short* __restrict__ yz,
                                              const unsigned* __restrict__ pedges,
                                              const int* __restrict__ gcur,
                                              const float* __restrict__ bl,
                                              unsigned short* __restrict__ h) {
    __shared__ unsigned esrc[ECAP];          // 10.5 KB
    __shared__ int hcnt[128], hoff[128], hcur[128];
    const int tid = threadIdx.x, lane = tid & 63, wv = tid >> 6;
    const int bkt = blockIdx.x;
    int cnt = gcur[bkt]; if (cnt > ECAP) cnt = ECAP;
    const size_t base = (size_t)bkt * ECAP;
    if (tid < 128) hcnt[tid] = 0;
    __syncthreads();
    for (int i = tid; i < cnt; i += 512)
        atomicAdd(&hcnt[pedges[base + i] & 127], 1);
    __syncthreads();
    if (tid < 64) {
        int a = hcnt[2 * tid], b = hcnt[2 * tid + 1];
        int s = a + b;
#pragma unroll
        for (int d = 1; d < 64; d <<= 1) { int t = __shfl_up(s, d, 64); if (lane >= d) s += t; }
        int ex = s - (a + b);
        hoff[2 * tid] = ex;     hcur[2 * tid] = ex;
        hoff[2 * tid + 1] = ex + a; hcur[2 * tid + 1] = ex + a;
    }
    __syncthreads();
    for (int i = tid; i < cnt; i += 512) {
        unsigned e = pedges[base + i];
        int p = atomicAdd(&hcur[e & 127], 1);
        esrc[p] = e >> 7;
    }
    __syncthreads();
    const int q = lane >> 4;                 // edge slot of the quad
    const int f4 = (lane & 15) * 4;          // 4 features owned by this lane
    float4 blv = *(const float4*)(bl + f4);
    for (int loc = wv; loc < 128; loc += 8) {
        int node = bkt * 128 + loc;
        if (node >= N_NODES) break;
        int st = hoff[loc], dg = hcnt[loc];
        float s0 = 0.f, s1 = 0.f, s2 = 0.f, s3 = 0.f;
        int j = 0;
        for (; j + 8 <= dg; j += 8) {
            unsigned eA = esrc[st + j + q];
            unsigned eB = esrc[st + j + 4 + q];
            uint2 uA = *(const uint2*)(yz + (size_t)eA * 128 + f4);
            uint2 uB = *(const uint2*)(yz + (size_t)eB * 128 + f4);
            s0 += b2f(uA.x & 0xffff) + b2f(uB.x & 0xffff);
            s1 += b2f(uA.x >> 16)    + b2f(uB.x >> 16);
            s2 += b2f(uA.y & 0xffff) + b2f(uB.y & 0xffff);
            s3 += b2f(uA.y >> 16)    + b2f(uB.y >> 16);
        }
        if (j + 4 <= dg) {
            unsigned eA = esrc[st + j + q];
            uint2 uA = *(const uint2*)(yz + (size_t)eA * 128 + f4);
            s0 += b2f(uA.x & 0xffff);
            s1 += b2f(uA.x >> 16);
            s2 += b2f(uA.y & 0xffff);
            s3 += b2f(uA.y >> 16);
            j += 4;
        }
        int rem = dg - j;
        if (q < rem) {
            unsigned eA = esrc[st + j + q];
            uint2 uA = *(const uint2*)(yz + (size_t)eA * 128 + f4);
            s0 += b2f(uA.x & 0xffff);
            s1 += b2f(uA.x >> 16);
            s2 += b2f(uA.y & 0xffff);
            s3 += b2f(uA.y >> 16);
        }
        s0 += __shfl_xor(s0, 16); s0 += __shfl_xor(s0, 32);
        s1 += __shfl_xor(s1, 16); s1 += __shfl_xor(s1, 32);
        s2 += __shfl_xor(s2, 16); s2 += __shfl_xor(s2, 32);
        s3 += __shfl_xor(s3, 16); s3 += __shfl_xor(s3, 32);
        if (q == 0) {
            float inv = 1.0f / fmaxf((float)dg, 1.0f);
            uint2 zu = *(const uint2*)(yz + (size_t)node * 128 + HID + f4);
            float v0 = s0 * inv + b2f(zu.x & 0xffff) + blv.x;
            float v1 = s1 * inv + b2f(zu.x >> 16)    + blv.y;
            float v2 = s2 * inv + b2f(zu.y & 0xffff) + blv.z;
            float v3 = s3 * inv + b2f(zu.y >> 16)    + blv.w;
            uint2 hv;
            hv.x = (unsigned)f2bf(fmaxf(v0, 0.f)) | ((unsigned)f2bf(fmaxf(v1, 0.f)) << 16);
            hv.y = (unsigned)f2bf(fmaxf(v2, 0.f)) | ((unsigned)f2bf(fmaxf(v3, 0.f)) << 16);
            *(uint2*)(h + (size_t)node * HID + f4) = hv;
        }
    }
}

// ------------------------------------------------------------------ fused2: out = h.Wo^T + bout (proven r6-r9)
__global__ __launch_bounds__(256, 2) void k_fused2(
    const unsigned short* __restrict__ h, const unsigned short* __restrict__ Wo,
    const float* __restrict__ bout, float* __restrict__ out) {

    __shared__ float sout[64 * OUT_F];       // 75 KB
    const int tid = threadIdx.x;
    const int lane = tid & 63;
    const int mt = tid >> 6;
    const int nb = blockIdx.x * 64;
    const int lm = lane & 15, lk = lane >> 4;

    int row = nb + mt * 16 + lm;
    if (row >= N_NODES) row = N_NODES - 1;
    bf8 ah[2];
#pragma unroll
    for (int k2 = 0; k2 < 2; ++k2)
        ah[k2] = *reinterpret_cast<const bf8*>(h + (size_t)row * HID + k2 * 32 + lk * 8);

    for (int g = 0; g < 5; ++g) {
        f32x4 acc2[4];
#pragma unroll
        for (int b = 0; b < 4; ++b) acc2[b] = f32x4{0.f, 0.f, 0.f, 0.f};
#pragma unroll
        for (int k2 = 0; k2 < 2; ++k2) {
            bf8 bw[4];
#pragma unroll
            for (int nt = 0; nt < 4; ++nt)
                bw[nt] = *reinterpret_cast<const bf8*>(
                    Wo + (size_t)((g * 4 + nt) * 16 + lm) * HID + k2 * 32 + lk * 8);
#pragma unroll
            for (int nt = 0; nt < 4; ++nt)
                acc2[nt] = __builtin_amdgcn_mfma_f32_16x16x32_bf16(ah[k2], bw[nt], acc2[nt], 0, 0, 0);
        }
#pragma unroll
        for (int nt = 0; nt < 4; ++nt) {
            int o = g * 64 + nt * 16 + lm;
            if (o < OUT_F) {
                float bo = bout[o];
#pragma unroll
                for (int r = 0; r < 4; ++r) {
                    int locn = mt * 16 + lk * 4 + r;
                    sout[locn * OUT_F + o] = acc2[nt][r] + bo;
                }
            }
        }
    }
    __syncthreads();
    const int nvalid = min(64, N_NODES - nb);
    const int total = nvalid * OUT_F;
    float* op = out + (size_t)nb * OUT_F;
    for (int i = tid; i < total; i += 256) op[i] = sout[i];
}

extern "C" void kernel_launch(void* const* d_in, const int* in_sizes, int n_in,
                              void* d_out, int out_size, void* d_ws, size_t ws_size,
                              hipStream_t stream) {
    const float* x    = (const float*)d_in[0];
    const int*   ei   = (const int*)d_in[1];
    const float* Wl   = (const float*)d_in[2];
    const float* bl   = (const float*)d_in[3];
    const float* Wr   = (const float*)d_in[4];
    const float* Wout = (const float*)d_in[5];
    const float* bout = (const float*)d_in[6];
    float* out = (float*)d_out;

    int nE = in_sizes[1] / 2;

    unsigned short* yz = (unsigned short*)d_ws;                   // 25.6 MB
    unsigned short* h  = yz + (size_t)N_NODES * 128;              // 12.8 MB
    unsigned* pedges = (unsigned*)(h + (size_t)N_NODES * HID);    // 8.41 MB (NBKT*ECAP)
    int* gcur  = (int*)(pedges + (size_t)NBKT * ECAP);
    unsigned short* Wc = (unsigned short*)(gcur + NBKT);          // 128*128
    unsigned short* Wo = Wc + 128 * 128;                          // 320*64

    int prep_n = 128 * 128 + WO_ROWS * HID + NBKT;
    k_prep<<<(prep_n + 255) / 256, 256, 0, stream>>>(Wl, Wr, Wout, Wc, Wo, gcur);
    k_pg<<<PART_BLOCKS + GEMM_BLOCKS, 512, 0, stream>>>(ei, gcur, pedges, nE, x, Wc, yz);
    k_agg3<<<NBKT, 512, 0, stream>>>(yz, pedges, gcur, bl, h);
    k_fused2<<<(N_NODES + 63) / 64, 256, 0, stream>>>(h, Wo, bout, out);
}